// Round 7
// baseline (564.501 us; speedup 1.0000x reference)
//
#include <hip/hip_runtime.h>
#include <hip/hip_fp16.h>

#define N_NODES 100000
#define N_EDGES 1600000
#define IN_DIM  165
#define HIDDEN  128
#define OUT_DIM 2

#define NBKT 196        // ceil(100000/512) buckets of 512 nodes
#define CHUNK 8192      // edges per k_part block
#define KPAD 176        // 5*32 + 16
#define NSLICE 8        // feature slices (16 features each, 3.2 MB table/slice)
#define NB16 6250       // 100000/16 nodes-blocks per slice in k_agg1

typedef _Float16 half8_t __attribute__((ext_vector_type(8)));
typedef _Float16 half4_t __attribute__((ext_vector_type(4)));
typedef float floatx4 __attribute__((ext_vector_type(4)));

// ---------------- degree histogram ----------------

__global__ void k_hist(const int* __restrict__ dst, int* __restrict__ deg) {
    int e4 = blockIdx.x * blockDim.x + threadIdx.x;
    if (e4 < N_EDGES / 4) {
        int4 d = ((const int4*)dst)[e4];
        atomicAdd(&deg[d.x], 1);
        atomicAdd(&deg[d.y], 1);
        atomicAdd(&deg[d.z], 1);
        atomicAdd(&deg[d.w], 1);
    }
}

// ---------------- scan: deg -> rowptr + dinv ----------------

__global__ __launch_bounds__(1024) void k_scan(const int* __restrict__ deg,
                                               int* __restrict__ rowptr,
                                               float* __restrict__ dinv) {
    __shared__ int wsum[16];
    __shared__ int chunk_total;
    const int NI4 = N_NODES / 4;              // 25000
    const int NCH = (NI4 + 1023) / 1024;      // 25
    int t = threadIdx.x;
    int lane = t & 63, wid = t >> 6;
    const int4* deg4 = (const int4*)deg;
    int running = 0;
    int idx4 = t;
    int4 cur = (idx4 < NI4) ? deg4[idx4] : make_int4(0, 0, 0, 0);
    for (int c = 0; c < NCH; c++) {
        int nidx4 = idx4 + 1024;
        int4 nxt = make_int4(0, 0, 0, 0);
        if (c + 1 < NCH && nidx4 < NI4) nxt = deg4[nidx4];
        int s = cur.x + cur.y + cur.z + cur.w;
        int inc = s;
        #pragma unroll
        for (int off = 1; off < 64; off <<= 1) {
            int y = __shfl_up(inc, off);
            if (lane >= off) inc += y;
        }
        if (lane == 63) wsum[wid] = inc;
        __syncthreads();
        if (t == 0) {
            int acc = 0;
            for (int w = 0; w < 16; w++) { int v = wsum[w]; wsum[w] = acc; acc += v; }
            chunk_total = acc;
        }
        __syncthreads();
        int e = running + wsum[wid] + (inc - s);
        if (idx4 < NI4) {
            int4 r;
            r.x = e;
            r.y = e + cur.x;
            r.z = r.y + cur.y;
            r.w = r.z + cur.z;
            ((int4*)rowptr)[idx4] = r;
            float4 dv;
            dv.x = rsqrtf((float)(cur.x + 1));
            dv.y = rsqrtf((float)(cur.y + 1));
            dv.z = rsqrtf((float)(cur.z + 1));
            dv.w = rsqrtf((float)(cur.w + 1));
            ((float4*)dinv)[idx4] = dv;
        }
        running += chunk_total;
        __syncthreads();
        cur = nxt;
        idx4 = nidx4;
    }
    if (t == 0) rowptr[N_NODES] = running;
}

// ---------------- bucket cursor init ----------------

__global__ void k_binit(const int* __restrict__ rowptr, int* __restrict__ bcursor) {
    int b = blockIdx.x * blockDim.x + threadIdx.x;
    if (b < NBKT) bcursor[b] = rowptr[b << 9];
}

// ---------------- phase 1: block-local counting sort by coarse bucket ----------------
// entry = src | (dst&511)<<17  (26 bits)

__global__ __launch_bounds__(256) void k_part(const int* __restrict__ src,
                                              const int* __restrict__ dst,
                                              int* __restrict__ bcursor,
                                              unsigned* __restrict__ csr_tmp) {
    __shared__ unsigned stage[CHUNK];   // 32 KB
    __shared__ int hist[256];           // counts (NBKT used)
    __shared__ int startv[256];         // exclusive scan
    __shared__ int lcur[256];           // scatter cursor
    __shared__ int gbase[256];          // claimed global base
    __shared__ int wsum[4];

    int t = threadIdx.x;
    int lane = t & 63, wid = t >> 6;
    int e0 = blockIdx.x * CHUNK;
    int nE = N_EDGES - e0; if (nE > CHUNK) nE = CHUNK;

    hist[t] = 0;
    __syncthreads();

    for (int i = t; i < nE; i += 256)
        atomicAdd(&hist[dst[e0 + i] >> 9], 1);
    __syncthreads();

    // 256-wide exclusive scan of hist
    int v = hist[t];
    int inc = v;
    #pragma unroll
    for (int off = 1; off < 64; off <<= 1) {
        int y = __shfl_up(inc, off);
        if (lane >= off) inc += y;
    }
    if (lane == 63) wsum[wid] = inc;
    __syncthreads();
    if (t == 0) {
        int acc = 0;
        #pragma unroll
        for (int w = 0; w < 4; w++) { int tv = wsum[w]; wsum[w] = acc; acc += tv; }
    }
    __syncthreads();
    int excl = wsum[wid] + inc - v;
    startv[t] = excl;
    lcur[t] = excl;
    if (t < NBKT && v > 0) gbase[t] = atomicAdd(&bcursor[t], v);
    __syncthreads();

    // scatter entries into LDS stage, grouped by bucket
    for (int i = t; i < nE; i += 256) {
        int d = dst[e0 + i];
        int s = src[e0 + i];
        int bk = d >> 9;
        unsigned entry = (unsigned)s | ((unsigned)(d & 511) << 17);
        int pos = atomicAdd(&lcur[bk], 1);
        stage[pos] = entry;
    }
    __syncthreads();

    // coalesced per-segment write-out (wave per bucket round-robin)
    for (int bk = wid; bk < NBKT; bk += 4) {
        int cnt = hist[bk];
        int lo = startv[bk];
        int gb = gbase[bk];
        for (int j = lane; j < cnt; j += 64)
            csr_tmp[gb + j] = stage[lo + j];
    }
}

// ---------------- phase 2: in-bucket counting sort -> final CSR (src only) ----------------

__global__ __launch_bounds__(256) void k_sort2(const int* __restrict__ rowptr,
                                               const unsigned* __restrict__ csr_tmp,
                                               int* __restrict__ csr) {
    __shared__ int cur[512];
    int b = blockIdx.x;
    int n0 = b << 9;
    int t = threadIdx.x;
    #pragma unroll
    for (int j = 0; j < 2; j++) {
        int node = n0 + t + j * 256;
        cur[t + j * 256] = (node < N_NODES) ? rowptr[node] : 0;
    }
    int rbase = rowptr[n0];
    int rend  = rowptr[min(n0 + 512, N_NODES)];
    __syncthreads();
    for (int p = rbase + t; p < rend; p += 256) {
        unsigned entry = csr_tmp[p];
        int local = (int)(entry >> 17);
        int s = (int)(entry & 0x1FFFFu);
        int pos = atomicAdd(&cur[local], 1);
        csr[pos] = s;   // scatter confined to this bucket's ~33KB region
    }
}

// ---------------- W1 transpose to fp16 [col][KPAD] ----------------

__global__ void k_w1t(const float* __restrict__ W1, _Float16* __restrict__ w1t) {
    int idx = blockIdx.x * 256 + threadIdx.x;
    if (idx < HIDDEN * KPAD) {
        int c = idx / KPAD, k = idx - c * KPAD;
        float v = (k < IN_DIM) ? W1[k * HIDDEN + c] : 0.f;
        w1t[idx] = (_Float16)v;
    }
}

// ---------------- GEMM1 (f16 MFMA): h1b[slice][node][16] = dinv * (x @ W1) ----------------
// One wave per 16-row strip; A from global x (fp32->fp16), B from L2-resident W1T.
// Output in slice-blocked layout: slice = col/16 -> 3.2 MB contiguous per slice.

__global__ __launch_bounds__(256) void k_gemm1(const float* __restrict__ x,
                                               const _Float16* __restrict__ w1t,
                                               const float* __restrict__ dinv,
                                               _Float16* __restrict__ h1b) {
    int t = threadIdx.x;
    int wid = t >> 6, lane = t & 63;
    int row0 = (blockIdx.x * 4 + wid) * 16;
    if (row0 >= N_NODES) return;
    int m = lane & 15;
    int quad = lane >> 4;
    const float* xrow = x + (size_t)(row0 + m) * IN_DIM;

    floatx4 acc[8];
    #pragma unroll
    for (int i = 0; i < 8; i++) acc[i] = (floatx4)(0.f);

    #pragma unroll 1
    for (int kc = 0; kc < 5; kc++) {
        int kb = kc * 32 + quad * 8;
        half8_t a;
        #pragma unroll
        for (int j = 0; j < 8; j++) a[j] = (_Float16)xrow[kb + j];
        #pragma unroll
        for (int cb = 0; cb < 8; cb++) {
            int col = cb * 16 + m;
            half8_t bf = *(const half8_t*)&w1t[col * KPAD + kb];
            acc[cb] = __builtin_amdgcn_mfma_f32_16x16x32_f16(a, bf, acc[cb], 0, 0, 0);
        }
    }
    // K tail: 160..164 via 16x16x16 (k = quad*4 + j)
    {
        int kb = 160 + quad * 4;
        half4_t a;
        #pragma unroll
        for (int j = 0; j < 4; j++)
            a[j] = (kb + j < IN_DIM) ? (_Float16)xrow[kb + j] : (_Float16)0.f;
        #pragma unroll
        for (int cb = 0; cb < 8; cb++) {
            int col = cb * 16 + m;
            half4_t bf = *(const half4_t*)&w1t[col * KPAD + kb];
            acc[cb] = __builtin_amdgcn_mfma_f32_16x16x16f16(a, bf, acc[cb], 0, 0, 0);
        }
    }
    // epilogue: scale by dinv[row], store fp16 into slice-blocked layout
    float dv[4];
    #pragma unroll
    for (int r = 0; r < 4; r++) dv[r] = dinv[row0 + quad * 4 + r];
    #pragma unroll
    for (int cb = 0; cb < 8; cb++) {
        _Float16* base = h1b + (size_t)cb * (N_NODES * 16);
        #pragma unroll
        for (int r = 0; r < 4; r++) {
            base[(row0 + quad * 4 + r) * 16 + m] = (_Float16)(acc[cb][r] * dv[r]);
        }
    }
}

// ---------------- sliced agg1: per slice, gather 16-feature rows (L2-resident) ----------------
// wave = 1 node; lane = (edge 0..7) x (flane 0..7, half2 = 2 features).
// writes partial W2 dot (a0,a1) per (slice,node).

__global__ __launch_bounds__(256) void k_agg1(const __half2* __restrict__ h1b,
                                              const int* __restrict__ rowptr,
                                              const int* __restrict__ csr,
                                              const float* __restrict__ dinv,
                                              const float* __restrict__ b1,
                                              const float* __restrict__ W2,
                                              float2* __restrict__ h2part) {
    int bid = blockIdx.x;
    int slice = bid / NB16;
    int nb = bid - slice * NB16;
    int wid = threadIdx.x >> 6, lane = threadIdx.x & 63;
    int elane = lane >> 3, flane = lane & 7;
    const __half2* tab = h1b + (size_t)slice * (N_NODES * 8);
    float4 w2v = ((const float4*)W2)[slice * 8 + flane];
    float2 bb = ((const float2*)b1)[slice * 8 + flane];
    float2* outp = h2part + (size_t)slice * N_NODES;

    #pragma unroll 1
    for (int k = 0; k < 4; k++) {
        int node = nb * 16 + wid * 4 + k;
        int p0 = rowptr[node], p1 = rowptr[node + 1];
        float accx = 0.f, accy = 0.f;
        int p = p0;
        for (; p + 16 <= p1; p += 16) {
            int s0 = __builtin_nontemporal_load(csr + p + elane);
            int s1 = __builtin_nontemporal_load(csr + p + 8 + elane);
            __half2 g0 = tab[s0 * 8 + flane];
            __half2 g1 = tab[s1 * 8 + flane];
            float2 f0 = __half22float2(g0);
            float2 f1 = __half22float2(g1);
            accx += f0.x + f1.x;
            accy += f0.y + f1.y;
        }
        for (; p < p1; p += 8) {
            int e = p + elane;
            if (e < p1) {
                int s = __builtin_nontemporal_load(csr + e);
                float2 f = __half22float2(tab[s * 8 + flane]);
                accx += f.x;
                accy += f.y;
            }
        }
        // reduce across edge lanes (lane bits 3..5)
        #pragma unroll
        for (int off = 8; off <= 32; off <<= 1) {
            accx += __shfl_xor(accx, off);
            accy += __shfl_xor(accy, off);
        }
        float2 self = __half22float2(tab[node * 8 + flane]);
        float di = dinv[node];
        float z0 = fmaf(di, self.x + accx, bb.x);
        float z1 = fmaf(di, self.y + accy, bb.y);
        float r0 = fmaxf(z0, 0.f);
        float r1 = fmaxf(z1, 0.f);
        float a0 = r0 * w2v.x + r1 * w2v.z;
        float a1 = r0 * w2v.y + r1 * w2v.w;
        // reduce across feature lanes (lane bits 0..2)
        #pragma unroll
        for (int off = 1; off <= 4; off <<= 1) {
            a0 += __shfl_xor(a0, off);
            a1 += __shfl_xor(a1, off);
        }
        if (lane == 0) outp[node] = make_float2(a0, a1);
    }
}

// ---------------- reduce slice partials: h2s = dinv * sum_s h2part[s] ----------------

__global__ void k_red(const float2* __restrict__ h2part, const float* __restrict__ dinv,
                      float2* __restrict__ h2s) {
    int i = blockIdx.x * blockDim.x + threadIdx.x;
    if (i >= N_NODES) return;
    float sx = 0.f, sy = 0.f;
    #pragma unroll
    for (int s = 0; s < NSLICE; s++) {
        float2 v = h2part[(size_t)s * N_NODES + i];
        sx += v.x;
        sy += v.y;
    }
    float di = dinv[i];
    h2s[i] = make_float2(di * sx, di * sy);
}

// ---------------- agg2: out = b2 + dinv_i*(h2s_i + sum h2s_src) ----------------

__global__ void k_agg2(const float2* __restrict__ h2s, const int* __restrict__ rowptr,
                       const int* __restrict__ csr, const float* __restrict__ dinv,
                       const float* __restrict__ b2, float2* __restrict__ out) {
    int i = blockIdx.x * blockDim.x + threadIdx.x;
    if (i >= N_NODES) return;
    float2 self = h2s[i];
    float a0 = self.x, a1 = self.y;
    int p0 = rowptr[i], p1 = rowptr[i + 1];
    int p = p0;
    for (; p + 3 < p1; p += 4) {
        int s0 = csr[p], s1 = csr[p + 1], s2 = csr[p + 2], s3 = csr[p + 3];
        float2 g0 = h2s[s0], g1 = h2s[s1], g2 = h2s[s2], g3 = h2s[s3];
        a0 += g0.x + g1.x + g2.x + g3.x;
        a1 += g0.y + g1.y + g2.y + g3.y;
    }
    for (; p < p1; p++) {
        float2 g = h2s[csr[p]];
        a0 += g.x;
        a1 += g.y;
    }
    float di = dinv[i];
    out[i] = make_float2(fmaf(di, a0, b2[0]), fmaf(di, a1, b2[1]));
}

// ---------------- launch ----------------

extern "C" void kernel_launch(void* const* d_in, const int* in_sizes, int n_in,
                              void* d_out, int out_size, void* d_ws, size_t ws_size,
                              hipStream_t stream) {
    const float* x  = (const float*)d_in[0];
    const int*   ei = (const int*)d_in[1];
    const float* W1 = (const float*)d_in[2];
    const float* b1 = (const float*)d_in[3];
    const float* W2 = (const float*)d_in[4];
    const float* b2 = (const float*)d_in[5];
    float* out = (float*)d_out;

    const int* src = ei;
    const int* dst = ei + N_EDGES;

    char* ws = (char*)d_ws;
    size_t off = 0;
    auto alloc = [&](size_t bytes) -> void* {
        void* p = ws + off;
        off += (bytes + 255) & ~(size_t)255;
        return p;
    };
    _Float16* h1b   = (_Float16*)alloc((size_t)N_NODES * HIDDEN * 2);  // 25.6 MB (slice-blocked)
    int*      deg   = (int*)     alloc((size_t)N_NODES * 4);
    float*    dinv  = (float*)   alloc((size_t)N_NODES * 4);
    int*      rowptr= (int*)     alloc((size_t)(N_NODES + 1) * 4);
    int*      bcur  = (int*)     alloc((size_t)NBKT * 4);
    unsigned* csrt  = (unsigned*)alloc((size_t)N_EDGES * 4);           // 6.4 MB
    int*      csr   = (int*)     alloc((size_t)N_EDGES * 4);           // 6.4 MB
    _Float16* w1t   = (_Float16*)alloc((size_t)HIDDEN * KPAD * 2);     // 45 KB
    float2*   h2part= (float2*)  alloc((size_t)NSLICE * N_NODES * 8);  // 6.4 MB
    float2*   h2s   = (float2*)  alloc((size_t)N_NODES * 8);

    const int nchunks = (N_EDGES + CHUNK - 1) / CHUNK;  // 196

    (void)hipMemsetAsync(deg, 0, (size_t)N_NODES * 4, stream);
    k_hist<<<(N_EDGES / 4 + 255) / 256, 256, 0, stream>>>(dst, deg);
    k_scan<<<1, 1024, 0, stream>>>(deg, rowptr, dinv);
    k_binit<<<1, 256, 0, stream>>>(rowptr, bcur);
    k_part<<<nchunks, 256, 0, stream>>>(src, dst, bcur, csrt);
    k_sort2<<<NBKT, 256, 0, stream>>>(rowptr, csrt, csr);
    k_w1t<<<(HIDDEN * KPAD + 255) / 256, 256, 0, stream>>>(W1, w1t);
    k_gemm1<<<(N_NODES / 16 + 3) / 4, 256, 0, stream>>>(x, w1t, dinv, h1b);
    k_agg1<<<NSLICE * NB16, 256, 0, stream>>>((const __half2*)h1b, rowptr, csr, dinv, b1, W2, h2part);
    k_red<<<(N_NODES + 255) / 256, 256, 0, stream>>>(h2part, dinv, h2s);
    k_agg2<<<(N_NODES + 255) / 256, 256, 0, stream>>>(h2s, rowptr, csr, dinv, b2, (float2*)out);
}

// Round 8
// 365.529 us; speedup vs baseline: 1.5443x; 1.5443x over previous
//
#include <hip/hip_runtime.h>
#include <hip/hip_fp16.h>

#define N_NODES 100000
#define N_EDGES 1600000
#define IN_DIM  165
#define HIDDEN  128
#define OUT_DIM 2

#define NBKT 196        // ceil(100000/512) buckets of 512 nodes
#define CHUNK 8192      // edges per k_part block
#define KPAD 176        // 5*32 + 16
#define NI4 (N_NODES / 4)          // 25000 int4 elements
#define SCAN_BLOCKS ((NI4 + 255) / 256)   // 98

typedef _Float16 half8_t __attribute__((ext_vector_type(8)));
typedef _Float16 half4_t __attribute__((ext_vector_type(4)));
typedef float floatx4 __attribute__((ext_vector_type(4)));

// ---------------- degree histogram ----------------

__global__ void k_hist(const int* __restrict__ dst, int* __restrict__ deg) {
    int e4 = blockIdx.x * blockDim.x + threadIdx.x;
    if (e4 < N_EDGES / 4) {
        int4 d = ((const int4*)dst)[e4];
        atomicAdd(&deg[d.x], 1);
        atomicAdd(&deg[d.y], 1);
        atomicAdd(&deg[d.z], 1);
        atomicAdd(&deg[d.w], 1);
    }
}

// ---------------- hierarchical scan: deg -> rowptr + dinv + bucket cursors ------

__global__ __launch_bounds__(256) void k_scan1(const int* __restrict__ deg,
                                               int* __restrict__ bsum) {
    __shared__ int ws[4];
    int t = threadIdx.x, lane = t & 63, wid = t >> 6;
    int idx4 = blockIdx.x * 256 + t;
    int4 v = (idx4 < NI4) ? ((const int4*)deg)[idx4] : make_int4(0, 0, 0, 0);
    int s = v.x + v.y + v.z + v.w;
    #pragma unroll
    for (int off = 32; off; off >>= 1) s += __shfl_down(s, off);
    if (lane == 0) ws[wid] = s;
    __syncthreads();
    if (t == 0) bsum[blockIdx.x] = ws[0] + ws[1] + ws[2] + ws[3];
}

__global__ __launch_bounds__(128) void k_scan2(const int* __restrict__ bsum,
                                               int* __restrict__ boff) {
    __shared__ int w0tot;
    int t = threadIdx.x, lane = t & 63, wid = t >> 6;
    int v = (t < SCAN_BLOCKS) ? bsum[t] : 0;
    int inc = v;
    #pragma unroll
    for (int off = 1; off < 64; off <<= 1) {
        int y = __shfl_up(inc, off);
        if (lane >= off) inc += y;
    }
    if (wid == 0 && lane == 63) w0tot = inc;
    __syncthreads();
    int excl = inc - v + (wid ? w0tot : 0);
    if (t < SCAN_BLOCKS) boff[t] = excl;
}

__global__ __launch_bounds__(256) void k_scan3(const int* __restrict__ deg,
                                               const int* __restrict__ boff,
                                               int* __restrict__ rowptr,
                                               float* __restrict__ dinv,
                                               int* __restrict__ bcursor) {
    __shared__ int wsum[4];
    int t = threadIdx.x, lane = t & 63, wid = t >> 6;
    int idx4 = blockIdx.x * 256 + t;
    int4 cur = (idx4 < NI4) ? ((const int4*)deg)[idx4] : make_int4(0, 0, 0, 0);
    int s = cur.x + cur.y + cur.z + cur.w;
    int inc = s;
    #pragma unroll
    for (int off = 1; off < 64; off <<= 1) {
        int y = __shfl_up(inc, off);
        if (lane >= off) inc += y;
    }
    if (lane == 63) wsum[wid] = inc;
    __syncthreads();
    if (t == 0) {
        int acc = 0;
        #pragma unroll
        for (int w = 0; w < 4; w++) { int v = wsum[w]; wsum[w] = acc; acc += v; }
    }
    __syncthreads();
    int e = boff[blockIdx.x] + wsum[wid] + (inc - s);
    if (idx4 < NI4) {
        int4 r;
        r.x = e;
        r.y = e + cur.x;
        r.z = r.y + cur.y;
        r.w = r.z + cur.z;
        ((int4*)rowptr)[idx4] = r;
        float4 dv;
        dv.x = rsqrtf((float)(cur.x + 1));
        dv.y = rsqrtf((float)(cur.y + 1));
        dv.z = rsqrtf((float)(cur.z + 1));
        dv.w = rsqrtf((float)(cur.w + 1));
        ((float4*)dinv)[idx4] = dv;
        if ((idx4 & 127) == 0) bcursor[idx4 >> 7] = r.x;   // node = idx4*4 ≡ 0 mod 512
        if (idx4 == NI4 - 1) rowptr[N_NODES] = r.w + cur.w;
    }
}

// ---------------- phase 1: block-local counting sort by coarse bucket ----------------
// entry = src | (dst&511)<<17  (26 bits)

__global__ __launch_bounds__(256) void k_part(const int* __restrict__ src,
                                              const int* __restrict__ dst,
                                              int* __restrict__ bcursor,
                                              unsigned* __restrict__ csr_tmp) {
    __shared__ unsigned stage[CHUNK];   // 32 KB
    __shared__ int hist[256];           // counts (NBKT used)
    __shared__ int startv[256];         // exclusive scan
    __shared__ int lcur[256];           // scatter cursor
    __shared__ int gbase[256];          // claimed global base
    __shared__ int wsum[4];

    int t = threadIdx.x;
    int lane = t & 63, wid = t >> 6;
    int e0 = blockIdx.x * CHUNK;
    int nE = N_EDGES - e0; if (nE > CHUNK) nE = CHUNK;

    hist[t] = 0;
    __syncthreads();

    for (int i = t; i < nE; i += 256)
        atomicAdd(&hist[dst[e0 + i] >> 9], 1);
    __syncthreads();

    // 256-wide exclusive scan of hist
    int v = hist[t];
    int inc = v;
    #pragma unroll
    for (int off = 1; off < 64; off <<= 1) {
        int y = __shfl_up(inc, off);
        if (lane >= off) inc += y;
    }
    if (lane == 63) wsum[wid] = inc;
    __syncthreads();
    if (t == 0) {
        int acc = 0;
        #pragma unroll
        for (int w = 0; w < 4; w++) { int tv = wsum[w]; wsum[w] = acc; acc += tv; }
    }
    __syncthreads();
    int excl = wsum[wid] + inc - v;
    startv[t] = excl;
    lcur[t] = excl;
    if (t < NBKT && v > 0) gbase[t] = atomicAdd(&bcursor[t], v);
    __syncthreads();

    // scatter entries into LDS stage, grouped by bucket
    for (int i = t; i < nE; i += 256) {
        int d = dst[e0 + i];
        int s = src[e0 + i];
        int bk = d >> 9;
        unsigned entry = (unsigned)s | ((unsigned)(d & 511) << 17);
        int pos = atomicAdd(&lcur[bk], 1);
        stage[pos] = entry;
    }
    __syncthreads();

    // coalesced per-segment write-out (wave per bucket round-robin)
    for (int bk = wid; bk < NBKT; bk += 4) {
        int cnt = hist[bk];
        int lo = startv[bk];
        int gb = gbase[bk];
        for (int j = lane; j < cnt; j += 64)
            csr_tmp[gb + j] = stage[lo + j];
    }
}

// ---------------- phase 2: in-bucket counting sort -> final CSR (src only) ----------------

__global__ __launch_bounds__(256) void k_sort2(const int* __restrict__ rowptr,
                                               const unsigned* __restrict__ csr_tmp,
                                               int* __restrict__ csr) {
    __shared__ int cur[512];
    int b = blockIdx.x;
    int n0 = b << 9;
    int t = threadIdx.x;
    #pragma unroll
    for (int j = 0; j < 2; j++) {
        int node = n0 + t + j * 256;
        cur[t + j * 256] = (node < N_NODES) ? rowptr[node] : 0;
    }
    int rbase = rowptr[n0];
    int rend  = rowptr[min(n0 + 512, N_NODES)];
    __syncthreads();
    for (int p = rbase + t; p < rend; p += 256) {
        unsigned entry = csr_tmp[p];
        int local = (int)(entry >> 17);
        int s = (int)(entry & 0x1FFFFu);
        int pos = atomicAdd(&cur[local], 1);
        csr[pos] = s;   // scatter confined to this bucket's ~33KB region
    }
}

// ---------------- W1 transpose to fp16 [col][KPAD] ----------------

__global__ void k_w1t(const float* __restrict__ W1, _Float16* __restrict__ w1t) {
    int idx = blockIdx.x * 256 + threadIdx.x;
    if (idx < HIDDEN * KPAD) {
        int c = idx / KPAD, k = idx - c * KPAD;
        float v = (k < IN_DIM) ? W1[k * HIDDEN + c] : 0.f;
        w1t[idx] = (_Float16)v;
    }
}

// ---------------- GEMM1 (f16 MFMA): h1s = dinv * (x @ W1), fp16 row-major out ----------------

__global__ __launch_bounds__(256) void k_gemm1(const float* __restrict__ x,
                                               const _Float16* __restrict__ w1t,
                                               const float* __restrict__ dinv,
                                               _Float16* __restrict__ h1s) {
    int t = threadIdx.x;
    int wid = t >> 6, lane = t & 63;
    int row0 = (blockIdx.x * 4 + wid) * 16;
    if (row0 >= N_NODES) return;
    int m = lane & 15;
    int quad = lane >> 4;
    const float* xrow = x + (size_t)(row0 + m) * IN_DIM;

    floatx4 acc[8];
    #pragma unroll
    for (int i = 0; i < 8; i++) acc[i] = (floatx4)(0.f);

    #pragma unroll 1
    for (int kc = 0; kc < 5; kc++) {
        int kb = kc * 32 + quad * 8;
        half8_t a;
        #pragma unroll
        for (int j = 0; j < 8; j++) a[j] = (_Float16)xrow[kb + j];
        #pragma unroll
        for (int cb = 0; cb < 8; cb++) {
            int col = cb * 16 + m;
            half8_t bf = *(const half8_t*)&w1t[col * KPAD + kb];
            acc[cb] = __builtin_amdgcn_mfma_f32_16x16x32_f16(a, bf, acc[cb], 0, 0, 0);
        }
    }
    // K tail: 160..164 via 16x16x16 (k = quad*4 + j)
    {
        int kb = 160 + quad * 4;
        half4_t a;
        #pragma unroll
        for (int j = 0; j < 4; j++)
            a[j] = (kb + j < IN_DIM) ? (_Float16)xrow[kb + j] : (_Float16)0.f;
        #pragma unroll
        for (int cb = 0; cb < 8; cb++) {
            int col = cb * 16 + m;
            half4_t bf = *(const half4_t*)&w1t[col * KPAD + kb];
            acc[cb] = __builtin_amdgcn_mfma_f32_16x16x16f16(a, bf, acc[cb], 0, 0, 0);
        }
    }
    // epilogue: scale by dinv[row], store fp16 (C/D: col=lane&15, row=quad*4+reg)
    float dv[4];
    #pragma unroll
    for (int r = 0; r < 4; r++) dv[r] = dinv[row0 + quad * 4 + r];
    #pragma unroll
    for (int cb = 0; cb < 8; cb++) {
        #pragma unroll
        for (int r = 0; r < 4; r++) {
            h1s[(size_t)(row0 + quad * 4 + r) * HIDDEN + cb * 16 + m] =
                (_Float16)(acc[cb][r] * dv[r]);
        }
    }
}

// ---------------- Fused agg1 + bias + ReLU + W2 (128->2), weightless sum ----------------
// One wave per node; lane f owns features 2f,2f+1. h2s = dinv * (relu(z) @ W2).

__global__ __launch_bounds__(256) void k_agg1(const __half2* __restrict__ h1,
                                              const int* __restrict__ rowptr,
                                              const int* __restrict__ csr,
                                              const float* __restrict__ dinv,
                                              const float* __restrict__ b1,
                                              const float* __restrict__ W2,
                                              float2* __restrict__ h2s) {
    int node = blockIdx.x * 4 + (threadIdx.x >> 6);
    int f = threadIdx.x & 63;
    float2 self = __half22float2(h1[node * 64 + f]);
    float accx = self.x, accy = self.y;
    int p0 = rowptr[node], p1 = rowptr[node + 1];

    int p = p0;
    for (; p + 7 < p1; p += 8) {
        int s[8];
        #pragma unroll
        for (int j = 0; j < 8; j++) s[j] = __builtin_nontemporal_load(csr + p + j);
        __half2 g[8];
        #pragma unroll
        for (int j = 0; j < 8; j++) g[j] = h1[s[j] * 64 + f];
        #pragma unroll
        for (int j = 0; j < 8; j++) {
            float2 gf = __half22float2(g[j]);
            accx += gf.x;
            accy += gf.y;
        }
    }
    for (; p < p1; p++) {
        int s = __builtin_nontemporal_load(csr + p);
        float2 gf = __half22float2(h1[s * 64 + f]);
        accx += gf.x;
        accy += gf.y;
    }

    float di = dinv[node];
    float2 bb = ((const float2*)b1)[f];
    float z0 = fmaf(di, accx, bb.x);
    float z1 = fmaf(di, accy, bb.y);
    float r0 = fmaxf(z0, 0.f);
    float r1 = fmaxf(z1, 0.f);
    float4 w2v = ((const float4*)W2)[f];
    float a0 = r0 * w2v.x + r1 * w2v.z;
    float a1 = r0 * w2v.y + r1 * w2v.w;
    #pragma unroll
    for (int off = 32; off; off >>= 1) {
        a0 += __shfl_down(a0, off);
        a1 += __shfl_down(a1, off);
    }
    if (f == 0) h2s[node] = make_float2(di * a0, di * a1);
}

// ---------------- agg2: out = b2 + dinv_i*(h2s_i + sum h2s_src) ----------------

__global__ void k_agg2(const float2* __restrict__ h2s, const int* __restrict__ rowptr,
                       const int* __restrict__ csr, const float* __restrict__ dinv,
                       const float* __restrict__ b2, float2* __restrict__ out) {
    int i = blockIdx.x * blockDim.x + threadIdx.x;
    if (i >= N_NODES) return;
    float2 self = h2s[i];
    float a0 = self.x, a1 = self.y;
    int p0 = rowptr[i], p1 = rowptr[i + 1];
    int p = p0;
    for (; p + 3 < p1; p += 4) {
        int s0 = __builtin_nontemporal_load(csr + p);
        int s1 = __builtin_nontemporal_load(csr + p + 1);
        int s2 = __builtin_nontemporal_load(csr + p + 2);
        int s3 = __builtin_nontemporal_load(csr + p + 3);
        float2 g0 = h2s[s0], g1 = h2s[s1], g2 = h2s[s2], g3 = h2s[s3];
        a0 += g0.x + g1.x + g2.x + g3.x;
        a1 += g0.y + g1.y + g2.y + g3.y;
    }
    for (; p < p1; p++) {
        float2 g = h2s[__builtin_nontemporal_load(csr + p)];
        a0 += g.x;
        a1 += g.y;
    }
    float di = dinv[i];
    out[i] = make_float2(fmaf(di, a0, b2[0]), fmaf(di, a1, b2[1]));
}

// ---------------- launch ----------------

extern "C" void kernel_launch(void* const* d_in, const int* in_sizes, int n_in,
                              void* d_out, int out_size, void* d_ws, size_t ws_size,
                              hipStream_t stream) {
    const float* x  = (const float*)d_in[0];
    const int*   ei = (const int*)d_in[1];
    const float* W1 = (const float*)d_in[2];
    const float* b1 = (const float*)d_in[3];
    const float* W2 = (const float*)d_in[4];
    const float* b2 = (const float*)d_in[5];
    float* out = (float*)d_out;

    const int* src = ei;
    const int* dst = ei + N_EDGES;

    char* ws = (char*)d_ws;
    size_t off = 0;
    auto alloc = [&](size_t bytes) -> void* {
        void* p = ws + off;
        off += (bytes + 255) & ~(size_t)255;
        return p;
    };
    _Float16* h1s   = (_Float16*)alloc((size_t)N_NODES * HIDDEN * 2);  // 25.6 MB
    int*      deg   = (int*)     alloc((size_t)N_NODES * 4);
    float*    dinv  = (float*)   alloc((size_t)N_NODES * 4);
    int*      rowptr= (int*)     alloc((size_t)(N_NODES + 1) * 4);
    int*      bcur  = (int*)     alloc((size_t)NBKT * 4);
    int*      bsum  = (int*)     alloc((size_t)SCAN_BLOCKS * 4);
    int*      boff  = (int*)     alloc((size_t)SCAN_BLOCKS * 4);
    unsigned* csrt  = (unsigned*)alloc((size_t)N_EDGES * 4);           // 6.4 MB
    int*      csr   = (int*)     alloc((size_t)N_EDGES * 4);           // 6.4 MB
    _Float16* w1t   = (_Float16*)alloc((size_t)HIDDEN * KPAD * 2);     // 45 KB
    float2*   h2s   = (float2*)  alloc((size_t)N_NODES * 8);

    const int nchunks = (N_EDGES + CHUNK - 1) / CHUNK;  // 196

    (void)hipMemsetAsync(deg, 0, (size_t)N_NODES * 4, stream);
    k_hist<<<(N_EDGES / 4 + 255) / 256, 256, 0, stream>>>(dst, deg);
    k_scan1<<<SCAN_BLOCKS, 256, 0, stream>>>(deg, bsum);
    k_scan2<<<1, 128, 0, stream>>>(bsum, boff);
    k_scan3<<<SCAN_BLOCKS, 256, 0, stream>>>(deg, boff, rowptr, dinv, bcur);
    k_part<<<nchunks, 256, 0, stream>>>(src, dst, bcur, csrt);
    k_sort2<<<NBKT, 256, 0, stream>>>(rowptr, csrt, csr);
    k_w1t<<<(HIDDEN * KPAD + 255) / 256, 256, 0, stream>>>(W1, w1t);
    k_gemm1<<<(N_NODES / 16 + 3) / 4, 256, 0, stream>>>(x, w1t, dinv, h1s);
    k_agg1<<<N_NODES / 4, 256, 0, stream>>>((const __half2*)h1s, rowptr, csr, dinv, b1, W2, h2s);
    k_agg2<<<(N_NODES + 255) / 256, 256, 0, stream>>>(h2s, rowptr, csr, dinv, b2, (float2*)out);
}

// Round 9
// 292.625 us; speedup vs baseline: 1.9291x; 1.2491x over previous
//
#include <hip/hip_runtime.h>
#include <hip/hip_fp16.h>

#define N_NODES 100000
#define N_EDGES 1600000
#define IN_DIM  165
#define HIDDEN  128
#define OUT_DIM 2

#define NBKT 196        // ceil(100000/512) buckets of 512 nodes
#define CHUNK 8192      // edges per partition block
#define NCHUNK ((N_EDGES + CHUNK - 1) / CHUNK)   // 196
#define KPAD 176        // 5*32 + 16
#define GH_N (NBKT * NCHUNK)      // 38416
#define GH_N4 (GH_N / 4)          // 9604 (divisible: 38416 = 4*9604)

typedef _Float16 half8_t __attribute__((ext_vector_type(8)));
typedef _Float16 half4_t __attribute__((ext_vector_type(4)));
typedef float floatx4 __attribute__((ext_vector_type(4)));

// ---------------- phase 0: per-chunk coarse-bucket histogram (no global atomics) ----

__global__ __launch_bounds__(256) void k_part1(const int* __restrict__ dst,
                                               int* __restrict__ ghist) {
    __shared__ int hist[256];
    int t = threadIdx.x;
    hist[t] = 0;
    __syncthreads();
    int e0 = blockIdx.x * CHUNK;
    int nE = N_EDGES - e0; if (nE > CHUNK) nE = CHUNK;
    for (int i = t; i < nE; i += 256)
        atomicAdd(&hist[dst[e0 + i] >> 9], 1);
    __syncthreads();
    if (t < NBKT) ghist[t * NCHUNK + blockIdx.x] = hist[t];   // bucket-major
}

// ---------------- exclusive scan of ghist (38416 ints, single block) ----------------
// goff[b*NCHUNK + c] = global write base for chunk c's bucket-b segment.
// bucketptr[b] = start of bucket b in csr_tmp; bucketptr[NBKT] = N_EDGES.

__global__ __launch_bounds__(1024) void k_bscan(const int* __restrict__ ghist,
                                                int* __restrict__ goff,
                                                int* __restrict__ bucketptr) {
    __shared__ int wsum[16];
    __shared__ int chunk_total;
    const int NCH = (GH_N4 + 1023) / 1024;   // 10
    int t = threadIdx.x;
    int lane = t & 63, wid = t >> 6;
    const int4* g4 = (const int4*)ghist;
    int running = 0;
    int idx4 = t;
    int4 cur = (idx4 < GH_N4) ? g4[idx4] : make_int4(0, 0, 0, 0);
    for (int c = 0; c < NCH; c++) {
        int nidx4 = idx4 + 1024;
        int4 nxt = make_int4(0, 0, 0, 0);
        if (c + 1 < NCH && nidx4 < GH_N4) nxt = g4[nidx4];
        int s = cur.x + cur.y + cur.z + cur.w;
        int inc = s;
        #pragma unroll
        for (int off = 1; off < 64; off <<= 1) {
            int y = __shfl_up(inc, off);
            if (lane >= off) inc += y;
        }
        if (lane == 63) wsum[wid] = inc;
        __syncthreads();
        if (t == 0) {
            int acc = 0;
            #pragma unroll
            for (int w = 0; w < 16; w++) { int v = wsum[w]; wsum[w] = acc; acc += v; }
            chunk_total = acc;
        }
        __syncthreads();
        int e = running + wsum[wid] + (inc - s);
        if (idx4 < GH_N4) {
            int4 r;
            r.x = e;
            r.y = e + cur.x;
            r.z = r.y + cur.y;
            r.w = r.z + cur.z;
            ((int4*)goff)[idx4] = r;
            if (idx4 % 49 == 0) bucketptr[idx4 / 49] = r.x;   // NCHUNK/4 = 49
        }
        running += chunk_total;
        __syncthreads();
        cur = nxt;
        idx4 = nidx4;
    }
    if (t == 0) bucketptr[NBKT] = running;
}

// ---------------- phase 1: block-local counting sort by coarse bucket ----------------
// entry = src | (dst&511)<<17  (26 bits). No global atomics: bases from goff.

__global__ __launch_bounds__(256) void k_part2(const int* __restrict__ src,
                                               const int* __restrict__ dst,
                                               const int* __restrict__ goff,
                                               unsigned* __restrict__ csr_tmp) {
    __shared__ unsigned stage[CHUNK];   // 32 KB
    __shared__ int hist[256];
    __shared__ int startv[256];
    __shared__ int lcur[256];
    __shared__ int gbase[256];
    __shared__ int wsum[4];

    int t = threadIdx.x;
    int lane = t & 63, wid = t >> 6;
    int e0 = blockIdx.x * CHUNK;
    int nE = N_EDGES - e0; if (nE > CHUNK) nE = CHUNK;

    hist[t] = 0;
    if (t < NBKT) gbase[t] = goff[t * NCHUNK + blockIdx.x];
    __syncthreads();

    for (int i = t; i < nE; i += 256)
        atomicAdd(&hist[dst[e0 + i] >> 9], 1);
    __syncthreads();

    // 256-wide exclusive scan of hist
    int v = hist[t];
    int inc = v;
    #pragma unroll
    for (int off = 1; off < 64; off <<= 1) {
        int y = __shfl_up(inc, off);
        if (lane >= off) inc += y;
    }
    if (lane == 63) wsum[wid] = inc;
    __syncthreads();
    if (t == 0) {
        int acc = 0;
        #pragma unroll
        for (int w = 0; w < 4; w++) { int tv = wsum[w]; wsum[w] = acc; acc += tv; }
    }
    __syncthreads();
    int excl = wsum[wid] + inc - v;
    startv[t] = excl;
    lcur[t] = excl;
    __syncthreads();

    // scatter entries into LDS stage, grouped by bucket
    for (int i = t; i < nE; i += 256) {
        int d = dst[e0 + i];
        int s = src[e0 + i];
        int bk = d >> 9;
        unsigned entry = (unsigned)s | ((unsigned)(d & 511) << 17);
        int pos = atomicAdd(&lcur[bk], 1);
        stage[pos] = entry;
    }
    __syncthreads();

    // coalesced per-segment write-out (wave per bucket round-robin)
    for (int bk = wid; bk < NBKT; bk += 4) {
        int cnt = hist[bk];
        int lo = startv[bk];
        int gb = gbase[bk];
        for (int j = lane; j < cnt; j += 64)
            csr_tmp[gb + j] = stage[lo + j];
    }
}

// ---------------- phase 2: per-bucket sort; produces rowptr + dinv + csr ----------------

__global__ __launch_bounds__(256) void k_sort3(const unsigned* __restrict__ csr_tmp,
                                               const int* __restrict__ bucketptr,
                                               int* __restrict__ csr,
                                               int* __restrict__ rowptr,
                                               float* __restrict__ dinv) {
    __shared__ int cnt[512];
    __shared__ int cur[512];
    __shared__ int wsum[4];
    int b = blockIdx.x;
    int n0 = b << 9;
    int t = threadIdx.x;
    int lane = t & 63, wid = t >> 6;
    int rbase = bucketptr[b], rend = bucketptr[b + 1];

    cnt[t] = 0;
    cnt[t + 256] = 0;
    __syncthreads();
    for (int p = rbase + t; p < rend; p += 256)
        atomicAdd(&cnt[csr_tmp[p] >> 17], 1);
    __syncthreads();

    // 512-entry exclusive scan with 256 threads (thread t owns locals 2t, 2t+1)
    int c0 = cnt[2 * t], c1 = cnt[2 * t + 1];
    int s = c0 + c1;
    int inc = s;
    #pragma unroll
    for (int off = 1; off < 64; off <<= 1) {
        int y = __shfl_up(inc, off);
        if (lane >= off) inc += y;
    }
    if (lane == 63) wsum[wid] = inc;
    __syncthreads();
    if (t == 0) {
        int acc = 0;
        #pragma unroll
        for (int w = 0; w < 4; w++) { int tv = wsum[w]; wsum[w] = acc; acc += tv; }
    }
    __syncthreads();
    int base = rbase + wsum[wid] + (inc - s);
    cur[2 * t] = base;
    cur[2 * t + 1] = base + c0;
    int node0 = n0 + 2 * t;
    if (node0 < N_NODES) {
        rowptr[node0] = base;
        dinv[node0] = rsqrtf((float)(c0 + 1));
    }
    if (node0 + 1 < N_NODES) {
        rowptr[node0 + 1] = base + c0;
        dinv[node0 + 1] = rsqrtf((float)(c1 + 1));
    }
    if (b == NBKT - 1 && t == 0) rowptr[N_NODES] = rend;
    __syncthreads();

    for (int p = rbase + t; p < rend; p += 256) {
        unsigned entry = csr_tmp[p];
        int local = (int)(entry >> 17);
        int sv = (int)(entry & 0x1FFFFu);
        int pos = atomicAdd(&cur[local], 1);
        csr[pos] = sv;   // scatter confined to this bucket's ~33KB region
    }
}

// ---------------- W1 transpose to fp16 [col][KPAD] ----------------

__global__ void k_w1t(const float* __restrict__ W1, _Float16* __restrict__ w1t) {
    int idx = blockIdx.x * 256 + threadIdx.x;
    if (idx < HIDDEN * KPAD) {
        int c = idx / KPAD, k = idx - c * KPAD;
        float v = (k < IN_DIM) ? W1[k * HIDDEN + c] : 0.f;
        w1t[idx] = (_Float16)v;
    }
}

// ---------------- GEMM1 (f16 MFMA): h1s = dinv * (x @ W1), fp16 row-major out ----------------

__global__ __launch_bounds__(256) void k_gemm1(const float* __restrict__ x,
                                               const _Float16* __restrict__ w1t,
                                               const float* __restrict__ dinv,
                                               _Float16* __restrict__ h1s) {
    int t = threadIdx.x;
    int wid = t >> 6, lane = t & 63;
    int row0 = (blockIdx.x * 4 + wid) * 16;
    if (row0 >= N_NODES) return;
    int m = lane & 15;
    int quad = lane >> 4;
    const float* xrow = x + (size_t)(row0 + m) * IN_DIM;

    floatx4 acc[8];
    #pragma unroll
    for (int i = 0; i < 8; i++) acc[i] = (floatx4)(0.f);

    #pragma unroll 1
    for (int kc = 0; kc < 5; kc++) {
        int kb = kc * 32 + quad * 8;
        half8_t a;
        #pragma unroll
        for (int j = 0; j < 8; j++) a[j] = (_Float16)xrow[kb + j];
        #pragma unroll
        for (int cb = 0; cb < 8; cb++) {
            int col = cb * 16 + m;
            half8_t bf = *(const half8_t*)&w1t[col * KPAD + kb];
            acc[cb] = __builtin_amdgcn_mfma_f32_16x16x32_f16(a, bf, acc[cb], 0, 0, 0);
        }
    }
    // K tail: 160..164 via 16x16x16 (k = quad*4 + j)
    {
        int kb = 160 + quad * 4;
        half4_t a;
        #pragma unroll
        for (int j = 0; j < 4; j++)
            a[j] = (kb + j < IN_DIM) ? (_Float16)xrow[kb + j] : (_Float16)0.f;
        #pragma unroll
        for (int cb = 0; cb < 8; cb++) {
            int col = cb * 16 + m;
            half4_t bf = *(const half4_t*)&w1t[col * KPAD + kb];
            acc[cb] = __builtin_amdgcn_mfma_f32_16x16x16f16(a, bf, acc[cb], 0, 0, 0);
        }
    }
    // epilogue: scale by dinv[row], store fp16 (C/D: col=lane&15, row=quad*4+reg)
    float dv[4];
    #pragma unroll
    for (int r = 0; r < 4; r++) dv[r] = dinv[row0 + quad * 4 + r];
    #pragma unroll
    for (int cb = 0; cb < 8; cb++) {
        #pragma unroll
        for (int r = 0; r < 4; r++) {
            h1s[(size_t)(row0 + quad * 4 + r) * HIDDEN + cb * 16 + m] =
                (_Float16)(acc[cb][r] * dv[r]);
        }
    }
}

// ---------------- Fused agg1 + bias + ReLU + W2 (128->2), weightless sum ----------------
// One wave per node; lane f owns features 2f,2f+1. h2s = dinv * (relu(z) @ W2).

__global__ __launch_bounds__(256) void k_agg1(const __half2* __restrict__ h1,
                                              const int* __restrict__ rowptr,
                                              const int* __restrict__ csr,
                                              const float* __restrict__ dinv,
                                              const float* __restrict__ b1,
                                              const float* __restrict__ W2,
                                              float2* __restrict__ h2s) {
    int node = blockIdx.x * 4 + (threadIdx.x >> 6);
    int f = threadIdx.x & 63;
    float2 self = __half22float2(h1[node * 64 + f]);
    float accx = self.x, accy = self.y;
    int p0 = rowptr[node], p1 = rowptr[node + 1];

    int p = p0;
    for (; p + 7 < p1; p += 8) {
        int s[8];
        #pragma unroll
        for (int j = 0; j < 8; j++) s[j] = csr[p + j];
        __half2 g[8];
        #pragma unroll
        for (int j = 0; j < 8; j++) g[j] = h1[s[j] * 64 + f];
        #pragma unroll
        for (int j = 0; j < 8; j++) {
            float2 gf = __half22float2(g[j]);
            accx += gf.x;
            accy += gf.y;
        }
    }
    for (; p < p1; p++) {
        float2 gf = __half22float2(h1[csr[p] * 64 + f]);
        accx += gf.x;
        accy += gf.y;
    }

    float di = dinv[node];
    float2 bb = ((const float2*)b1)[f];
    float z0 = fmaf(di, accx, bb.x);
    float z1 = fmaf(di, accy, bb.y);
    float r0 = fmaxf(z0, 0.f);
    float r1 = fmaxf(z1, 0.f);
    float4 w2v = ((const float4*)W2)[f];
    float a0 = r0 * w2v.x + r1 * w2v.z;
    float a1 = r0 * w2v.y + r1 * w2v.w;
    #pragma unroll
    for (int off = 32; off; off >>= 1) {
        a0 += __shfl_down(a0, off);
        a1 += __shfl_down(a1, off);
    }
    if (f == 0) h2s[node] = make_float2(di * a0, di * a1);
}

// ---------------- agg2: out = b2 + dinv_i*(h2s_i + sum h2s_src) ----------------

__global__ void k_agg2(const float2* __restrict__ h2s, const int* __restrict__ rowptr,
                       const int* __restrict__ csr, const float* __restrict__ dinv,
                       const float* __restrict__ b2, float2* __restrict__ out) {
    int i = blockIdx.x * blockDim.x + threadIdx.x;
    if (i >= N_NODES) return;
    float2 self = h2s[i];
    float a0 = self.x, a1 = self.y;
    int p0 = rowptr[i], p1 = rowptr[i + 1];
    int p = p0;
    for (; p + 3 < p1; p += 4) {
        int s0 = csr[p], s1 = csr[p + 1], s2 = csr[p + 2], s3 = csr[p + 3];
        float2 g0 = h2s[s0], g1 = h2s[s1], g2 = h2s[s2], g3 = h2s[s3];
        a0 += g0.x + g1.x + g2.x + g3.x;
        a1 += g0.y + g1.y + g2.y + g3.y;
    }
    for (; p < p1; p++) {
        float2 g = h2s[csr[p]];
        a0 += g.x;
        a1 += g.y;
    }
    float di = dinv[i];
    out[i] = make_float2(fmaf(di, a0, b2[0]), fmaf(di, a1, b2[1]));
}

// ---------------- launch ----------------

extern "C" void kernel_launch(void* const* d_in, const int* in_sizes, int n_in,
                              void* d_out, int out_size, void* d_ws, size_t ws_size,
                              hipStream_t stream) {
    const float* x  = (const float*)d_in[0];
    const int*   ei = (const int*)d_in[1];
    const float* W1 = (const float*)d_in[2];
    const float* b1 = (const float*)d_in[3];
    const float* W2 = (const float*)d_in[4];
    const float* b2 = (const float*)d_in[5];
    float* out = (float*)d_out;

    const int* src = ei;
    const int* dst = ei + N_EDGES;

    char* ws = (char*)d_ws;
    size_t off = 0;
    auto alloc = [&](size_t bytes) -> void* {
        void* p = ws + off;
        off += (bytes + 255) & ~(size_t)255;
        return p;
    };
    _Float16* h1s    = (_Float16*)alloc((size_t)N_NODES * HIDDEN * 2);  // 25.6 MB
    float*    dinv   = (float*)   alloc((size_t)N_NODES * 4);
    int*      rowptr = (int*)     alloc((size_t)(N_NODES + 1) * 4);
    int*      ghist  = (int*)     alloc((size_t)GH_N * 4);              // 150 KB
    int*      goff   = (int*)     alloc((size_t)GH_N * 4);              // 150 KB
    int*      bktptr = (int*)     alloc((size_t)(NBKT + 1) * 4);
    unsigned* csrt   = (unsigned*)alloc((size_t)N_EDGES * 4);           // 6.4 MB
    int*      csr    = (int*)     alloc((size_t)N_EDGES * 4);           // 6.4 MB
    _Float16* w1t    = (_Float16*)alloc((size_t)HIDDEN * KPAD * 2);     // 45 KB
    float2*   h2s    = (float2*)  alloc((size_t)N_NODES * 8);

    k_w1t<<<(HIDDEN * KPAD + 255) / 256, 256, 0, stream>>>(W1, w1t);
    k_part1<<<NCHUNK, 256, 0, stream>>>(dst, ghist);
    k_bscan<<<1, 1024, 0, stream>>>(ghist, goff, bktptr);
    k_part2<<<NCHUNK, 256, 0, stream>>>(src, dst, goff, csrt);
    k_sort3<<<NBKT, 256, 0, stream>>>(csrt, bktptr, csr, rowptr, dinv);
    k_gemm1<<<(N_NODES / 16 + 3) / 4, 256, 0, stream>>>(x, w1t, dinv, h1s);
    k_agg1<<<N_NODES / 4, 256, 0, stream>>>((const __half2*)h1s, rowptr, csr, dinv, b1, W2, h2s);
    k_agg2<<<(N_NODES + 255) / 256, 256, 0, stream>>>(h2s, rowptr, csr, dinv, b2, (float2*)out);
}

// Round 10
// 285.721 us; speedup vs baseline: 1.9757x; 1.0242x over previous
//
#include <hip/hip_runtime.h>
#include <hip/hip_fp16.h>

#define N_NODES 100000
#define N_EDGES 1600000
#define IN_DIM  165
#define HIDDEN  128
#define OUT_DIM 2

#define NBKT 196        // ceil(100000/512) buckets of 512 nodes
#define CHUNK 8192      // edges per partition block
#define NCHUNK ((N_EDGES + CHUNK - 1) / CHUNK)   // 196
#define PADCAP 10240    // arena slots per bucket (mean 8192, sigma 90 -> 22 sigma slack)
#define KPAD 176        // 5*32 + 16

typedef _Float16 half8_t __attribute__((ext_vector_type(8)));
typedef _Float16 half4_t __attribute__((ext_vector_type(4)));
typedef float floatx4 __attribute__((ext_vector_type(4)));

// ---------------- phase 1: block-local counting sort by coarse bucket ----------------
// entry = src | (dst&511)<<17  (26 bits). Bases claimed via bcnt atomics into padded arena.

__global__ __launch_bounds__(256) void k_part2(const int* __restrict__ src,
                                               const int* __restrict__ dst,
                                               int* __restrict__ bcnt,
                                               unsigned* __restrict__ arena) {
    __shared__ unsigned stage[CHUNK];   // 32 KB
    __shared__ int hist[256];
    __shared__ int startv[256];
    __shared__ int lcur[256];
    __shared__ int gbase[256];
    __shared__ int wsum[4];

    int t = threadIdx.x;
    int lane = t & 63, wid = t >> 6;
    int e0 = blockIdx.x * CHUNK;
    int nE = N_EDGES - e0; if (nE > CHUNK) nE = CHUNK;

    hist[t] = 0;
    __syncthreads();

    for (int i = t; i < nE; i += 256)
        atomicAdd(&hist[dst[e0 + i] >> 9], 1);
    __syncthreads();

    // 256-wide exclusive scan of hist
    int v = hist[t];
    int inc = v;
    #pragma unroll
    for (int off = 1; off < 64; off <<= 1) {
        int y = __shfl_up(inc, off);
        if (lane >= off) inc += y;
    }
    if (lane == 63) wsum[wid] = inc;
    __syncthreads();
    if (t == 0) {
        int acc = 0;
        #pragma unroll
        for (int w = 0; w < 4; w++) { int tv = wsum[w]; wsum[w] = acc; acc += tv; }
    }
    __syncthreads();
    int excl = wsum[wid] + inc - v;
    startv[t] = excl;
    lcur[t] = excl;
    if (t < NBKT && v > 0) gbase[t] = t * PADCAP + atomicAdd(&bcnt[t], v);
    __syncthreads();

    // scatter entries into LDS stage, grouped by bucket
    for (int i = t; i < nE; i += 256) {
        int d = dst[e0 + i];
        int s = src[e0 + i];
        int bk = d >> 9;
        unsigned entry = (unsigned)s | ((unsigned)(d & 511) << 17);
        int pos = atomicAdd(&lcur[bk], 1);
        stage[pos] = entry;
    }
    __syncthreads();

    // coalesced per-segment write-out (wave per bucket round-robin)
    for (int bk = wid; bk < NBKT; bk += 4) {
        int cnt = hist[bk];
        int lo = startv[bk];
        int gb = gbase[bk];
        for (int j = lane; j < cnt; j += 64)
            arena[gb + j] = stage[lo + j];
    }
}

// ---------------- tiny scan of bucket totals -> dense bucket bases ----------------

__global__ __launch_bounds__(256) void k_btot(const int* __restrict__ bcnt,
                                              int* __restrict__ bucketptr) {
    __shared__ int wsum[4];
    int t = threadIdx.x, lane = t & 63, wid = t >> 6;
    int v = (t < NBKT) ? bcnt[t] : 0;
    int inc = v;
    #pragma unroll
    for (int off = 1; off < 64; off <<= 1) {
        int y = __shfl_up(inc, off);
        if (lane >= off) inc += y;
    }
    if (lane == 63) wsum[wid] = inc;
    __syncthreads();
    if (t == 0) {
        int acc = 0;
        #pragma unroll
        for (int w = 0; w < 4; w++) { int tv = wsum[w]; wsum[w] = acc; acc += tv; }
    }
    __syncthreads();
    int excl = wsum[wid] + inc - v;
    if (t <= NBKT) bucketptr[t] = (t < NBKT) ? excl : N_EDGES;
}

// ---------------- phase 2: per-bucket sort; produces rowptr + dinv + csr ----------------

__global__ __launch_bounds__(256) void k_sort3(const unsigned* __restrict__ arena,
                                               const int* __restrict__ bcnt,
                                               const int* __restrict__ bucketptr,
                                               int* __restrict__ csr,
                                               int* __restrict__ rowptr,
                                               float* __restrict__ dinv) {
    __shared__ int cnt[512];
    __shared__ int cur[512];
    __shared__ int wsum[4];
    int b = blockIdx.x;
    int n0 = b << 9;
    int t = threadIdx.x;
    int lane = t & 63, wid = t >> 6;
    int total = bcnt[b];
    int abase = b * PADCAP;
    int dbase = bucketptr[b];

    cnt[t] = 0;
    cnt[t + 256] = 0;
    __syncthreads();
    for (int p = t; p < total; p += 256)
        atomicAdd(&cnt[arena[abase + p] >> 17], 1);
    __syncthreads();

    // 512-entry exclusive scan with 256 threads (thread t owns locals 2t, 2t+1)
    int c0 = cnt[2 * t], c1 = cnt[2 * t + 1];
    int s = c0 + c1;
    int inc = s;
    #pragma unroll
    for (int off = 1; off < 64; off <<= 1) {
        int y = __shfl_up(inc, off);
        if (lane >= off) inc += y;
    }
    if (lane == 63) wsum[wid] = inc;
    __syncthreads();
    if (t == 0) {
        int acc = 0;
        #pragma unroll
        for (int w = 0; w < 4; w++) { int tv = wsum[w]; wsum[w] = acc; acc += tv; }
    }
    __syncthreads();
    int base = dbase + wsum[wid] + (inc - s);
    cur[2 * t] = base;
    cur[2 * t + 1] = base + c0;
    int node0 = n0 + 2 * t;
    if (node0 < N_NODES) {
        rowptr[node0] = base;
        dinv[node0] = rsqrtf((float)(c0 + 1));
    }
    if (node0 + 1 < N_NODES) {
        rowptr[node0 + 1] = base + c0;
        dinv[node0 + 1] = rsqrtf((float)(c1 + 1));
    }
    if (b == NBKT - 1 && t == 0) rowptr[N_NODES] = N_EDGES;
    __syncthreads();

    for (int p = t; p < total; p += 256) {
        unsigned entry = arena[abase + p];
        int local = (int)(entry >> 17);
        int sv = (int)(entry & 0x1FFFFu);
        int pos = atomicAdd(&cur[local], 1);
        csr[pos] = sv;   // scatter confined to this bucket's ~33KB region
    }
}

// ---------------- W1 transpose to fp16 [col][KPAD] ----------------

__global__ void k_w1t(const float* __restrict__ W1, _Float16* __restrict__ w1t) {
    int idx = blockIdx.x * 256 + threadIdx.x;
    if (idx < HIDDEN * KPAD) {
        int c = idx / KPAD, k = idx - c * KPAD;
        float v = (k < IN_DIM) ? W1[k * HIDDEN + c] : 0.f;
        w1t[idx] = (_Float16)v;
    }
}

// ---------------- GEMM1 (f16 MFMA): h1s = dinv * (x @ W1), fp16 row-major out ----------------

__global__ __launch_bounds__(256) void k_gemm1(const float* __restrict__ x,
                                               const _Float16* __restrict__ w1t,
                                               const float* __restrict__ dinv,
                                               _Float16* __restrict__ h1s) {
    int t = threadIdx.x;
    int wid = t >> 6, lane = t & 63;
    int row0 = (blockIdx.x * 4 + wid) * 16;
    if (row0 >= N_NODES) return;
    int m = lane & 15;
    int quad = lane >> 4;
    const float* xrow = x + (size_t)(row0 + m) * IN_DIM;

    floatx4 acc[8];
    #pragma unroll
    for (int i = 0; i < 8; i++) acc[i] = (floatx4)(0.f);

    #pragma unroll
    for (int kc = 0; kc < 5; kc++) {
        int kb = kc * 32 + quad * 8;
        half8_t a;
        #pragma unroll
        for (int j = 0; j < 8; j++) a[j] = (_Float16)xrow[kb + j];
        #pragma unroll
        for (int cb = 0; cb < 8; cb++) {
            int col = cb * 16 + m;
            half8_t bf = *(const half8_t*)&w1t[col * KPAD + kb];
            acc[cb] = __builtin_amdgcn_mfma_f32_16x16x32_f16(a, bf, acc[cb], 0, 0, 0);
        }
    }
    // K tail: 160..164 via 16x16x16 (k = quad*4 + j)
    {
        int kb = 160 + quad * 4;
        half4_t a;
        #pragma unroll
        for (int j = 0; j < 4; j++)
            a[j] = (kb + j < IN_DIM) ? (_Float16)xrow[kb + j] : (_Float16)0.f;
        #pragma unroll
        for (int cb = 0; cb < 8; cb++) {
            int col = cb * 16 + m;
            half4_t bf = *(const half4_t*)&w1t[col * KPAD + kb];
            acc[cb] = __builtin_amdgcn_mfma_f32_16x16x16f16(a, bf, acc[cb], 0, 0, 0);
        }
    }
    // epilogue: scale by dinv[row], store fp16 (C/D: col=lane&15, row=quad*4+reg)
    float dv[4];
    #pragma unroll
    for (int r = 0; r < 4; r++) dv[r] = dinv[row0 + quad * 4 + r];
    #pragma unroll
    for (int cb = 0; cb < 8; cb++) {
        #pragma unroll
        for (int r = 0; r < 4; r++) {
            h1s[(size_t)(row0 + quad * 4 + r) * HIDDEN + cb * 16 + m] =
                (_Float16)(acc[cb][r] * dv[r]);
        }
    }
}

// ---------------- Fused agg1 + bias + ReLU + W2 (128->2), weightless sum ----------------
// One wave per node; lane f owns features 2f,2f+1. h2s = dinv * (relu(z) @ W2).

__global__ __launch_bounds__(256) void k_agg1(const __half2* __restrict__ h1,
                                              const int* __restrict__ rowptr,
                                              const int* __restrict__ csr,
                                              const float* __restrict__ dinv,
                                              const float* __restrict__ b1,
                                              const float* __restrict__ W2,
                                              float2* __restrict__ h2s) {
    int node = blockIdx.x * 4 + (threadIdx.x >> 6);
    int f = threadIdx.x & 63;
    float2 self = __half22float2(h1[node * 64 + f]);
    float accx = self.x, accy = self.y;
    int p0 = rowptr[node], p1 = rowptr[node + 1];

    int p = p0;
    for (; p + 7 < p1; p += 8) {
        int s[8];
        #pragma unroll
        for (int j = 0; j < 8; j++) s[j] = csr[p + j];
        __half2 g[8];
        #pragma unroll
        for (int j = 0; j < 8; j++) g[j] = h1[s[j] * 64 + f];
        #pragma unroll
        for (int j = 0; j < 8; j++) {
            float2 gf = __half22float2(g[j]);
            accx += gf.x;
            accy += gf.y;
        }
    }
    for (; p < p1; p++) {
        float2 gf = __half22float2(h1[csr[p] * 64 + f]);
        accx += gf.x;
        accy += gf.y;
    }

    float di = dinv[node];
    float2 bb = ((const float2*)b1)[f];
    float z0 = fmaf(di, accx, bb.x);
    float z1 = fmaf(di, accy, bb.y);
    float r0 = fmaxf(z0, 0.f);
    float r1 = fmaxf(z1, 0.f);
    float4 w2v = ((const float4*)W2)[f];
    float a0 = r0 * w2v.x + r1 * w2v.z;
    float a1 = r0 * w2v.y + r1 * w2v.w;
    #pragma unroll
    for (int off = 32; off; off >>= 1) {
        a0 += __shfl_down(a0, off);
        a1 += __shfl_down(a1, off);
    }
    if (f == 0) h2s[node] = make_float2(di * a0, di * a1);
}

// ---------------- agg2: out = b2 + dinv_i*(h2s_i + sum h2s_src) ----------------

__global__ void k_agg2(const float2* __restrict__ h2s, const int* __restrict__ rowptr,
                       const int* __restrict__ csr, const float* __restrict__ dinv,
                       const float* __restrict__ b2, float2* __restrict__ out) {
    int i = blockIdx.x * blockDim.x + threadIdx.x;
    if (i >= N_NODES) return;
    float2 self = h2s[i];
    float a0 = self.x, a1 = self.y;
    int p0 = rowptr[i], p1 = rowptr[i + 1];
    int p = p0;
    for (; p + 3 < p1; p += 4) {
        int s0 = csr[p], s1 = csr[p + 1], s2 = csr[p + 2], s3 = csr[p + 3];
        float2 g0 = h2s[s0], g1 = h2s[s1], g2 = h2s[s2], g3 = h2s[s3];
        a0 += g0.x + g1.x + g2.x + g3.x;
        a1 += g0.y + g1.y + g2.y + g3.y;
    }
    for (; p < p1; p++) {
        float2 g = h2s[csr[p]];
        a0 += g.x;
        a1 += g.y;
    }
    float di = dinv[i];
    out[i] = make_float2(fmaf(di, a0, b2[0]), fmaf(di, a1, b2[1]));
}

// ---------------- launch ----------------

extern "C" void kernel_launch(void* const* d_in, const int* in_sizes, int n_in,
                              void* d_out, int out_size, void* d_ws, size_t ws_size,
                              hipStream_t stream) {
    const float* x  = (const float*)d_in[0];
    const int*   ei = (const int*)d_in[1];
    const float* W1 = (const float*)d_in[2];
    const float* b1 = (const float*)d_in[3];
    const float* W2 = (const float*)d_in[4];
    const float* b2 = (const float*)d_in[5];
    float* out = (float*)d_out;

    const int* src = ei;
    const int* dst = ei + N_EDGES;

    char* ws = (char*)d_ws;
    size_t off = 0;
    auto alloc = [&](size_t bytes) -> void* {
        void* p = ws + off;
        off += (bytes + 255) & ~(size_t)255;
        return p;
    };
    _Float16* h1s    = (_Float16*)alloc((size_t)N_NODES * HIDDEN * 2);  // 25.6 MB
    float*    dinv   = (float*)   alloc((size_t)N_NODES * 4);
    int*      rowptr = (int*)     alloc((size_t)(N_NODES + 1) * 4);
    int*      bcnt   = (int*)     alloc((size_t)NBKT * 4);
    int*      bktptr = (int*)     alloc((size_t)(NBKT + 1) * 4);
    unsigned* arena  = (unsigned*)alloc((size_t)NBKT * PADCAP * 4);     // 8.0 MB
    int*      csr    = (int*)     alloc((size_t)N_EDGES * 4);           // 6.4 MB
    _Float16* w1t    = (_Float16*)alloc((size_t)HIDDEN * KPAD * 2);     // 45 KB
    float2*   h2s    = (float2*)  alloc((size_t)N_NODES * 8);

    (void)hipMemsetAsync(bcnt, 0, (size_t)NBKT * 4, stream);
    k_w1t<<<(HIDDEN * KPAD + 255) / 256, 256, 0, stream>>>(W1, w1t);
    k_part2<<<NCHUNK, 256, 0, stream>>>(src, dst, bcnt, arena);
    k_btot<<<1, 256, 0, stream>>>(bcnt, bktptr);
    k_sort3<<<NBKT, 256, 0, stream>>>(arena, bcnt, bktptr, csr, rowptr, dinv);
    k_gemm1<<<(N_NODES / 16 + 3) / 4, 256, 0, stream>>>(x, w1t, dinv, h1s);
    k_agg1<<<N_NODES / 4, 256, 0, stream>>>((const __half2*)h1s, rowptr, csr, dinv, b1, W2, h2s);
    k_agg2<<<(N_NODES + 255) / 256, 256, 0, stream>>>(h2s, rowptr, csr, dinv, b2, (float2*)out);
}

// Round 11
// 266.152 us; speedup vs baseline: 2.1210x; 1.0735x over previous
//
#include <hip/hip_runtime.h>
#include <hip/hip_fp16.h>

#define N_NODES 100000
#define N_EDGES 1600000
#define IN_DIM  165
#define HIDDEN  128
#define OUT_DIM 2

#define NBKT 196        // ceil(100000/512) buckets of 512 nodes
#define CHUNK 4096      // edges per partition block
#define NCHUNK ((N_EDGES + CHUNK - 1) / CHUNK)   // 391
#define PADCAP 10240    // arena slots per bucket (mean 8163, sigma ~90 -> 23 sigma slack)
#define KPAD 176        // 5*32 + 16

typedef _Float16 half8_t __attribute__((ext_vector_type(8)));
typedef _Float16 half4_t __attribute__((ext_vector_type(4)));
typedef float floatx4 __attribute__((ext_vector_type(4)));

// ---------------- phase 1: chunk hist -> claim -> direct scatter into padded arena ----
// entry = src | (dst&511)<<17  (26 bits)

__global__ __launch_bounds__(512) void k_part2(const int* __restrict__ src,
                                               const int* __restrict__ dst,
                                               int* __restrict__ bcnt,
                                               unsigned* __restrict__ arena) {
    __shared__ int hist[256];
    __shared__ int gbase[256];

    int t = threadIdx.x;
    int e0 = blockIdx.x * CHUNK;
    int nE = N_EDGES - e0; if (nE > CHUNK) nE = CHUNK;

    if (t < 256) hist[t] = 0;
    __syncthreads();

    for (int i = t; i < nE; i += 512)
        atomicAdd(&hist[dst[e0 + i] >> 9], 1);
    __syncthreads();

    if (t < NBKT) gbase[t] = t * PADCAP + atomicAdd(&bcnt[t], hist[t]);
    if (t < 256) hist[t] = 0;   // reuse as rank counter
    __syncthreads();

    for (int i = t; i < nE; i += 512) {
        int d = dst[e0 + i];
        int s = src[e0 + i];
        int bk = d >> 9;
        unsigned entry = (unsigned)s | ((unsigned)(d & 511) << 17);
        int idx = atomicAdd(&hist[bk], 1);
        arena[gbase[bk] + idx] = entry;   // 196 open segments/block -> L2 write-combines
    }
}

// ---------------- tiny scan of bucket totals -> dense bucket bases ----------------

__global__ __launch_bounds__(256) void k_btot(const int* __restrict__ bcnt,
                                              int* __restrict__ bucketptr) {
    __shared__ int wsum[4];
    int t = threadIdx.x, lane = t & 63, wid = t >> 6;
    int v = (t < NBKT) ? bcnt[t] : 0;
    int inc = v;
    #pragma unroll
    for (int off = 1; off < 64; off <<= 1) {
        int y = __shfl_up(inc, off);
        if (lane >= off) inc += y;
    }
    if (lane == 63) wsum[wid] = inc;
    __syncthreads();
    if (t == 0) {
        int acc = 0;
        #pragma unroll
        for (int w = 0; w < 4; w++) { int tv = wsum[w]; wsum[w] = acc; acc += tv; }
    }
    __syncthreads();
    int excl = wsum[wid] + inc - v;
    if (t <= NBKT) bucketptr[t] = (t < NBKT) ? excl : N_EDGES;
}

// ---------------- phase 2: per-bucket sort; produces rowptr + dinv + csr ----------------

__global__ __launch_bounds__(1024) void k_sort3(const unsigned* __restrict__ arena,
                                                const int* __restrict__ bcnt,
                                                const int* __restrict__ bucketptr,
                                                int* __restrict__ csr,
                                                int* __restrict__ rowptr,
                                                float* __restrict__ dinv) {
    __shared__ int cnt[512];
    __shared__ int cur[512];
    __shared__ int wsum[4];
    int b = blockIdx.x;
    int n0 = b << 9;
    int t = threadIdx.x;
    int lane = t & 63, wid = t >> 6;
    int total = bcnt[b];
    int abase = b * PADCAP;
    int dbase = bucketptr[b];

    if (t < 512) cnt[t] = 0;
    __syncthreads();
    for (int p = t; p < total; p += 1024)
        atomicAdd(&cnt[arena[abase + p] >> 17], 1);
    __syncthreads();

    // 512-entry exclusive scan using first 256 threads (thread t owns locals 2t, 2t+1)
    int c0 = 0, c1 = 0, s = 0, inc = 0;
    if (t < 256) {
        c0 = cnt[2 * t];
        c1 = cnt[2 * t + 1];
        s = c0 + c1;
        inc = s;
        #pragma unroll
        for (int off = 1; off < 64; off <<= 1) {
            int y = __shfl_up(inc, off);
            if (lane >= off) inc += y;
        }
        if (lane == 63) wsum[wid] = inc;
    }
    __syncthreads();
    if (t == 0) {
        int acc = 0;
        #pragma unroll
        for (int w = 0; w < 4; w++) { int tv = wsum[w]; wsum[w] = acc; acc += tv; }
    }
    __syncthreads();
    if (t < 256) {
        int base = dbase + wsum[wid] + (inc - s);
        cur[2 * t] = base;
        cur[2 * t + 1] = base + c0;
        int node0 = n0 + 2 * t;
        if (node0 < N_NODES) {
            rowptr[node0] = base;
            dinv[node0] = rsqrtf((float)(c0 + 1));
        }
        if (node0 + 1 < N_NODES) {
            rowptr[node0 + 1] = base + c0;
            dinv[node0 + 1] = rsqrtf((float)(c1 + 1));
        }
    }
    if (b == NBKT - 1 && t == 0) rowptr[N_NODES] = N_EDGES;
    __syncthreads();

    for (int p = t; p < total; p += 1024) {
        unsigned entry = arena[abase + p];
        int local = (int)(entry >> 17);
        int sv = (int)(entry & 0x1FFFFu);
        int pos = atomicAdd(&cur[local], 1);
        csr[pos] = sv;   // scatter confined to this bucket's ~33KB region
    }
}

// ---------------- W1 transpose to fp16 [col][KPAD] ----------------

__global__ void k_w1t(const float* __restrict__ W1, _Float16* __restrict__ w1t) {
    int idx = blockIdx.x * 256 + threadIdx.x;
    if (idx < HIDDEN * KPAD) {
        int c = idx / KPAD, k = idx - c * KPAD;
        float v = (k < IN_DIM) ? W1[k * HIDDEN + c] : 0.f;
        w1t[idx] = (_Float16)v;
    }
}

// ---------------- GEMM1 (f16 MFMA): h1s = dinv * (x @ W1), fp16 row-major out ----------------

__global__ __launch_bounds__(256) void k_gemm1(const float* __restrict__ x,
                                               const _Float16* __restrict__ w1t,
                                               const float* __restrict__ dinv,
                                               _Float16* __restrict__ h1s) {
    int t = threadIdx.x;
    int wid = t >> 6, lane = t & 63;
    int row0 = (blockIdx.x * 4 + wid) * 16;
    if (row0 >= N_NODES) return;
    int m = lane & 15;
    int quad = lane >> 4;
    const float* xrow = x + (size_t)(row0 + m) * IN_DIM;

    floatx4 acc[8];
    #pragma unroll
    for (int i = 0; i < 8; i++) acc[i] = (floatx4)(0.f);

    #pragma unroll
    for (int kc = 0; kc < 5; kc++) {
        int kb = kc * 32 + quad * 8;
        half8_t a;
        #pragma unroll
        for (int j = 0; j < 8; j++) a[j] = (_Float16)xrow[kb + j];
        #pragma unroll
        for (int cb = 0; cb < 8; cb++) {
            int col = cb * 16 + m;
            half8_t bf = *(const half8_t*)&w1t[col * KPAD + kb];
            acc[cb] = __builtin_amdgcn_mfma_f32_16x16x32_f16(a, bf, acc[cb], 0, 0, 0);
        }
    }
    // K tail: 160..164 via 16x16x16 (k = quad*4 + j)
    {
        int kb = 160 + quad * 4;
        half4_t a;
        #pragma unroll
        for (int j = 0; j < 4; j++)
            a[j] = (kb + j < IN_DIM) ? (_Float16)xrow[kb + j] : (_Float16)0.f;
        #pragma unroll
        for (int cb = 0; cb < 8; cb++) {
            int col = cb * 16 + m;
            half4_t bf = *(const half4_t*)&w1t[col * KPAD + kb];
            acc[cb] = __builtin_amdgcn_mfma_f32_16x16x16f16(a, bf, acc[cb], 0, 0, 0);
        }
    }
    // epilogue: scale by dinv[row], store fp16 (C/D: col=lane&15, row=quad*4+reg)
    float dv[4];
    #pragma unroll
    for (int r = 0; r < 4; r++) dv[r] = dinv[row0 + quad * 4 + r];
    #pragma unroll
    for (int cb = 0; cb < 8; cb++) {
        #pragma unroll
        for (int r = 0; r < 4; r++) {
            h1s[(size_t)(row0 + quad * 4 + r) * HIDDEN + cb * 16 + m] =
                (_Float16)(acc[cb][r] * dv[r]);
        }
    }
}

// ---------------- Fused agg1 + bias + ReLU + W2 (128->2), weightless sum ----------------
// One wave per node; lane f owns features 2f,2f+1. h2s = dinv * (relu(z) @ W2).

__global__ __launch_bounds__(256) void k_agg1(const __half2* __restrict__ h1,
                                              const int* __restrict__ rowptr,
                                              const int* __restrict__ csr,
                                              const float* __restrict__ dinv,
                                              const float* __restrict__ b1,
                                              const float* __restrict__ W2,
                                              float2* __restrict__ h2s) {
    int node = blockIdx.x * 4 + (threadIdx.x >> 6);
    int f = threadIdx.x & 63;
    float2 self = __half22float2(h1[node * 64 + f]);
    float accx = self.x, accy = self.y;
    int p0 = rowptr[node], p1 = rowptr[node + 1];

    int p = p0;
    for (; p + 7 < p1; p += 8) {
        int s[8];
        #pragma unroll
        for (int j = 0; j < 8; j++) s[j] = csr[p + j];
        __half2 g[8];
        #pragma unroll
        for (int j = 0; j < 8; j++) g[j] = h1[s[j] * 64 + f];
        #pragma unroll
        for (int j = 0; j < 8; j++) {
            float2 gf = __half22float2(g[j]);
            accx += gf.x;
            accy += gf.y;
        }
    }
    for (; p < p1; p++) {
        float2 gf = __half22float2(h1[csr[p] * 64 + f]);
        accx += gf.x;
        accy += gf.y;
    }

    float di = dinv[node];
    float2 bb = ((const float2*)b1)[f];
    float z0 = fmaf(di, accx, bb.x);
    float z1 = fmaf(di, accy, bb.y);
    float r0 = fmaxf(z0, 0.f);
    float r1 = fmaxf(z1, 0.f);
    float4 w2v = ((const float4*)W2)[f];
    float a0 = r0 * w2v.x + r1 * w2v.z;
    float a1 = r0 * w2v.y + r1 * w2v.w;
    #pragma unroll
    for (int off = 32; off; off >>= 1) {
        a0 += __shfl_down(a0, off);
        a1 += __shfl_down(a1, off);
    }
    if (f == 0) h2s[node] = make_float2(di * a0, di * a1);
}

// ---------------- agg2: out = b2 + dinv_i*(h2s_i + sum h2s_src) ----------------

__global__ void k_agg2(const float2* __restrict__ h2s, const int* __restrict__ rowptr,
                       const int* __restrict__ csr, const float* __restrict__ dinv,
                       const float* __restrict__ b2, float2* __restrict__ out) {
    int i = blockIdx.x * blockDim.x + threadIdx.x;
    if (i >= N_NODES) return;
    float2 self = h2s[i];
    float a0 = self.x, a1 = self.y;
    int p0 = rowptr[i], p1 = rowptr[i + 1];
    int p = p0;
    for (; p + 3 < p1; p += 4) {
        int s0 = csr[p], s1 = csr[p + 1], s2 = csr[p + 2], s3 = csr[p + 3];
        float2 g0 = h2s[s0], g1 = h2s[s1], g2 = h2s[s2], g3 = h2s[s3];
        a0 += g0.x + g1.x + g2.x + g3.x;
        a1 += g0.y + g1.y + g2.y + g3.y;
    }
    for (; p < p1; p++) {
        float2 g = h2s[csr[p]];
        a0 += g.x;
        a1 += g.y;
    }
    float di = dinv[i];
    out[i] = make_float2(fmaf(di, a0, b2[0]), fmaf(di, a1, b2[1]));
}

// ---------------- launch ----------------

extern "C" void kernel_launch(void* const* d_in, const int* in_sizes, int n_in,
                              void* d_out, int out_size, void* d_ws, size_t ws_size,
                              hipStream_t stream) {
    const float* x  = (const float*)d_in[0];
    const int*   ei = (const int*)d_in[1];
    const float* W1 = (const float*)d_in[2];
    const float* b1 = (const float*)d_in[3];
    const float* W2 = (const float*)d_in[4];
    const float* b2 = (const float*)d_in[5];
    float* out = (float*)d_out;

    const int* src = ei;
    const int* dst = ei + N_EDGES;

    char* ws = (char*)d_ws;
    size_t off = 0;
    auto alloc = [&](size_t bytes) -> void* {
        void* p = ws + off;
        off += (bytes + 255) & ~(size_t)255;
        return p;
    };
    _Float16* h1s    = (_Float16*)alloc((size_t)N_NODES * HIDDEN * 2);  // 25.6 MB
    float*    dinv   = (float*)   alloc((size_t)N_NODES * 4);
    int*      rowptr = (int*)     alloc((size_t)(N_NODES + 1) * 4);
    int*      bcnt   = (int*)     alloc((size_t)NBKT * 4);
    int*      bktptr = (int*)     alloc((size_t)(NBKT + 1) * 4);
    unsigned* arena  = (unsigned*)alloc((size_t)NBKT * PADCAP * 4);     // 8.0 MB
    int*      csr    = (int*)     alloc((size_t)N_EDGES * 4);           // 6.4 MB
    _Float16* w1t    = (_Float16*)alloc((size_t)HIDDEN * KPAD * 2);     // 45 KB
    float2*   h2s    = (float2*)  alloc((size_t)N_NODES * 8);

    (void)hipMemsetAsync(bcnt, 0, (size_t)NBKT * 4, stream);
    k_w1t<<<(HIDDEN * KPAD + 255) / 256, 256, 0, stream>>>(W1, w1t);
    k_part2<<<NCHUNK, 512, 0, stream>>>(src, dst, bcnt, arena);
    k_btot<<<1, 256, 0, stream>>>(bcnt, bktptr);
    k_sort3<<<NBKT, 1024, 0, stream>>>(arena, bcnt, bktptr, csr, rowptr, dinv);
    k_gemm1<<<(N_NODES / 16 + 3) / 4, 256, 0, stream>>>(x, w1t, dinv, h1s);
    k_agg1<<<N_NODES / 4, 256, 0, stream>>>((const __half2*)h1s, rowptr, csr, dinv, b1, W2, h2s);
    k_agg2<<<(N_NODES + 255) / 256, 256, 0, stream>>>(h2s, rowptr, csr, dinv, b2, (float2*)out);
}

// Round 12
// 260.630 us; speedup vs baseline: 2.1659x; 1.0212x over previous
//
#include <hip/hip_runtime.h>
#include <hip/hip_fp16.h>

#define N_NODES 100000
#define N_EDGES 1600000
#define IN_DIM  165
#define HIDDEN  128
#define OUT_DIM 2

#define NBKT 196        // ceil(100000/512) buckets of 512 nodes
#define CHUNK 4096      // edges per partition block
#define NCHUNK ((N_EDGES + CHUNK - 1) / CHUNK)   // 391
#define PADCAP 10240    // arena slots per bucket (mean 8163, sigma ~90 -> 23 sigma slack)
#define KPAD 176        // 5*32 + 16

typedef _Float16 half8_t __attribute__((ext_vector_type(8)));
typedef _Float16 half4_t __attribute__((ext_vector_type(4)));
typedef float floatx4 __attribute__((ext_vector_type(4)));
typedef float floatx4_a4 __attribute__((ext_vector_type(4), aligned(4)));  // under-aligned vec load

// ---------------- phase 1: chunk hist -> claim -> direct scatter into padded arena ----
// entry = src | (dst&511)<<17  (26 bits)

__global__ __launch_bounds__(512) void k_part2(const int* __restrict__ src,
                                               const int* __restrict__ dst,
                                               int* __restrict__ bcnt,
                                               unsigned* __restrict__ arena) {
    __shared__ int hist[256];
    __shared__ int gbase[256];

    int t = threadIdx.x;
    int e0 = blockIdx.x * CHUNK;
    int nE = N_EDGES - e0; if (nE > CHUNK) nE = CHUNK;
    int n4 = nE >> 2;                       // N_EDGES % 4 == 0, so no scalar tail
    const int4* dst4 = (const int4*)(dst + e0);
    const int4* src4 = (const int4*)(src + e0);

    if (t < 256) hist[t] = 0;
    __syncthreads();

    for (int i = t; i < n4; i += 512) {
        int4 d = dst4[i];
        atomicAdd(&hist[d.x >> 9], 1);
        atomicAdd(&hist[d.y >> 9], 1);
        atomicAdd(&hist[d.z >> 9], 1);
        atomicAdd(&hist[d.w >> 9], 1);
    }
    __syncthreads();

    if (t < NBKT) gbase[t] = t * PADCAP + atomicAdd(&bcnt[t], hist[t]);
    if (t < 256) hist[t] = 0;   // reuse as rank counter
    __syncthreads();

    for (int i = t; i < n4; i += 512) {
        int4 d = dst4[i];
        int4 s = src4[i];
        #pragma unroll
        for (int j = 0; j < 4; j++) {
            int dd = (j == 0) ? d.x : (j == 1) ? d.y : (j == 2) ? d.z : d.w;
            int ss = (j == 0) ? s.x : (j == 1) ? s.y : (j == 2) ? s.z : s.w;
            int bk = dd >> 9;
            unsigned entry = (unsigned)ss | ((unsigned)(dd & 511) << 17);
            int idx = atomicAdd(&hist[bk], 1);
            arena[gbase[bk] + idx] = entry;
        }
    }
}

// ---------------- tiny scan of bucket totals -> dense bucket bases ----------------

__global__ __launch_bounds__(256) void k_btot(const int* __restrict__ bcnt,
                                              int* __restrict__ bucketptr) {
    __shared__ int wsum[4];
    int t = threadIdx.x, lane = t & 63, wid = t >> 6;
    int v = (t < NBKT) ? bcnt[t] : 0;
    int inc = v;
    #pragma unroll
    for (int off = 1; off < 64; off <<= 1) {
        int y = __shfl_up(inc, off);
        if (lane >= off) inc += y;
    }
    if (lane == 63) wsum[wid] = inc;
    __syncthreads();
    if (t == 0) {
        int acc = 0;
        #pragma unroll
        for (int w = 0; w < 4; w++) { int tv = wsum[w]; wsum[w] = acc; acc += tv; }
    }
    __syncthreads();
    int excl = wsum[wid] + inc - v;
    if (t <= NBKT) bucketptr[t] = (t < NBKT) ? excl : N_EDGES;
}

// ---------------- phase 2: per-bucket sort; produces rowptr + dinv + csr ----------------

__global__ __launch_bounds__(1024) void k_sort3(const unsigned* __restrict__ arena,
                                                const int* __restrict__ bcnt,
                                                const int* __restrict__ bucketptr,
                                                int* __restrict__ csr,
                                                int* __restrict__ rowptr,
                                                float* __restrict__ dinv) {
    __shared__ int cnt[512];
    __shared__ int cur[512];
    __shared__ int wsum[4];
    int b = blockIdx.x;
    int n0 = b << 9;
    int t = threadIdx.x;
    int lane = t & 63, wid = t >> 6;
    int total = bcnt[b];
    int abase = b * PADCAP;        // PADCAP*4 bytes aligned -> int4-safe base
    int dbase = bucketptr[b];
    int nt4 = total >> 2;
    const uint4* arena4 = (const uint4*)(arena + abase);

    if (t < 512) cnt[t] = 0;
    __syncthreads();
    for (int p = t; p < nt4; p += 1024) {
        uint4 e = arena4[p];
        atomicAdd(&cnt[e.x >> 17], 1);
        atomicAdd(&cnt[e.y >> 17], 1);
        atomicAdd(&cnt[e.z >> 17], 1);
        atomicAdd(&cnt[e.w >> 17], 1);
    }
    {
        int p = (nt4 << 2) + t;
        if (p < total) atomicAdd(&cnt[arena[abase + p] >> 17], 1);
    }
    __syncthreads();

    // 512-entry exclusive scan using first 256 threads (thread t owns locals 2t, 2t+1)
    int c0 = 0, c1 = 0, s = 0, inc = 0;
    if (t < 256) {
        c0 = cnt[2 * t];
        c1 = cnt[2 * t + 1];
        s = c0 + c1;
        inc = s;
        #pragma unroll
        for (int off = 1; off < 64; off <<= 1) {
            int y = __shfl_up(inc, off);
            if (lane >= off) inc += y;
        }
        if (lane == 63) wsum[wid] = inc;
    }
    __syncthreads();
    if (t == 0) {
        int acc = 0;
        #pragma unroll
        for (int w = 0; w < 4; w++) { int tv = wsum[w]; wsum[w] = acc; acc += tv; }
    }
    __syncthreads();
    if (t < 256) {
        int base = dbase + wsum[wid] + (inc - s);
        cur[2 * t] = base;
        cur[2 * t + 1] = base + c0;
        int node0 = n0 + 2 * t;
        if (node0 < N_NODES) {
            rowptr[node0] = base;
            dinv[node0] = rsqrtf((float)(c0 + 1));
        }
        if (node0 + 1 < N_NODES) {
            rowptr[node0 + 1] = base + c0;
            dinv[node0 + 1] = rsqrtf((float)(c1 + 1));
        }
    }
    if (b == NBKT - 1 && t == 0) rowptr[N_NODES] = N_EDGES;
    __syncthreads();

    for (int p = t; p < nt4; p += 1024) {
        uint4 e = arena4[p];
        #pragma unroll
        for (int j = 0; j < 4; j++) {
            unsigned entry = (j == 0) ? e.x : (j == 1) ? e.y : (j == 2) ? e.z : e.w;
            int local = (int)(entry >> 17);
            int sv = (int)(entry & 0x1FFFFu);
            int pos = atomicAdd(&cur[local], 1);
            csr[pos] = sv;
        }
    }
    {
        int p = (nt4 << 2) + t;
        if (p < total) {
            unsigned entry = arena[abase + p];
            int local = (int)(entry >> 17);
            int sv = (int)(entry & 0x1FFFFu);
            int pos = atomicAdd(&cur[local], 1);
            csr[pos] = sv;
        }
    }
}

// ---------------- W1 transpose to fp16 [col][KPAD] ----------------

__global__ void k_w1t(const float* __restrict__ W1, _Float16* __restrict__ w1t) {
    int idx = blockIdx.x * 256 + threadIdx.x;
    if (idx < HIDDEN * KPAD) {
        int c = idx / KPAD, k = idx - c * KPAD;
        float v = (k < IN_DIM) ? W1[k * HIDDEN + c] : 0.f;
        w1t[idx] = (_Float16)v;
    }
}

// ---------------- GEMM1 (f16 MFMA): h1s = dinv * (x @ W1), fp16 row-major out ----------------

__global__ __launch_bounds__(256) void k_gemm1(const float* __restrict__ x,
                                               const _Float16* __restrict__ w1t,
                                               const float* __restrict__ dinv,
                                               _Float16* __restrict__ h1s) {
    int t = threadIdx.x;
    int wid = t >> 6, lane = t & 63;
    int row0 = (blockIdx.x * 4 + wid) * 16;
    if (row0 >= N_NODES) return;
    int m = lane & 15;
    int quad = lane >> 4;
    const float* xrow = x + (size_t)(row0 + m) * IN_DIM;

    floatx4 acc[8];
    #pragma unroll
    for (int i = 0; i < 8; i++) acc[i] = (floatx4)(0.f);

    #pragma unroll
    for (int kc = 0; kc < 5; kc++) {
        int kb = kc * 32 + quad * 8;       // max 152; +7 = 159 < 165 -> always in-row
        floatx4_a4 va = *(const floatx4_a4*)(xrow + kb);
        floatx4_a4 vb = *(const floatx4_a4*)(xrow + kb + 4);
        half8_t a;
        #pragma unroll
        for (int j = 0; j < 4; j++) a[j] = (_Float16)va[j];
        #pragma unroll
        for (int j = 0; j < 4; j++) a[4 + j] = (_Float16)vb[j];
        #pragma unroll
        for (int cb = 0; cb < 8; cb++) {
            int col = cb * 16 + m;
            half8_t bf = *(const half8_t*)&w1t[col * KPAD + kb];
            acc[cb] = __builtin_amdgcn_mfma_f32_16x16x32_f16(a, bf, acc[cb], 0, 0, 0);
        }
    }
    // K tail: 160..164 via 16x16x16 (k = quad*4 + j) -- scalar guarded loads (OOB-safe)
    {
        int kb = 160 + quad * 4;
        half4_t a;
        #pragma unroll
        for (int j = 0; j < 4; j++)
            a[j] = (kb + j < IN_DIM) ? (_Float16)xrow[kb + j] : (_Float16)0.f;
        #pragma unroll
        for (int cb = 0; cb < 8; cb++) {
            int col = cb * 16 + m;
            half4_t bf = *(const half4_t*)&w1t[col * KPAD + kb];
            acc[cb] = __builtin_amdgcn_mfma_f32_16x16x16f16(a, bf, acc[cb], 0, 0, 0);
        }
    }
    // epilogue: scale by dinv[row], store fp16 (C/D: col=lane&15, row=quad*4+reg)
    float dv[4];
    #pragma unroll
    for (int r = 0; r < 4; r++) dv[r] = dinv[row0 + quad * 4 + r];
    #pragma unroll
    for (int cb = 0; cb < 8; cb++) {
        #pragma unroll
        for (int r = 0; r < 4; r++) {
            h1s[(size_t)(row0 + quad * 4 + r) * HIDDEN + cb * 16 + m] =
                (_Float16)(acc[cb][r] * dv[r]);
        }
    }
}

// ---------------- Fused agg1 + bias + ReLU + W2 (128->2), weightless sum ----------------
// One wave per node; lane f owns features 2f,2f+1. h2s = dinv * (relu(z) @ W2).

__global__ __launch_bounds__(256) void k_agg1(const __half2* __restrict__ h1,
                                              const int* __restrict__ rowptr,
                                              const int* __restrict__ csr,
                                              const float* __restrict__ dinv,
                                              const float* __restrict__ b1,
                                              const float* __restrict__ W2,
                                              float2* __restrict__ h2s) {
    int node = blockIdx.x * 4 + (threadIdx.x >> 6);
    int f = threadIdx.x & 63;
    float2 self = __half22float2(h1[node * 64 + f]);
    float accx = self.x, accy = self.y;
    int p0 = rowptr[node], p1 = rowptr[node + 1];

    int p = p0;
    for (; p + 7 < p1; p += 8) {
        int s[8];
        #pragma unroll
        for (int j = 0; j < 8; j++) s[j] = csr[p + j];
        __half2 g[8];
        #pragma unroll
        for (int j = 0; j < 8; j++) g[j] = h1[s[j] * 64 + f];
        #pragma unroll
        for (int j = 0; j < 8; j++) {
            float2 gf = __half22float2(g[j]);
            accx += gf.x;
            accy += gf.y;
        }
    }
    for (; p < p1; p++) {
        float2 gf = __half22float2(h1[csr[p] * 64 + f]);
        accx += gf.x;
        accy += gf.y;
    }

    float di = dinv[node];
    float2 bb = ((const float2*)b1)[f];
    float z0 = fmaf(di, accx, bb.x);
    float z1 = fmaf(di, accy, bb.y);
    float r0 = fmaxf(z0, 0.f);
    float r1 = fmaxf(z1, 0.f);
    float4 w2v = ((const float4*)W2)[f];
    float a0 = r0 * w2v.x + r1 * w2v.z;
    float a1 = r0 * w2v.y + r1 * w2v.w;
    #pragma unroll
    for (int off = 32; off; off >>= 1) {
        a0 += __shfl_down(a0, off);
        a1 += __shfl_down(a1, off);
    }
    if (f == 0) h2s[node] = make_float2(di * a0, di * a1);
}

// ---------------- agg2: out = b2 + dinv_i*(h2s_i + sum h2s_src) ----------------
// 16 lanes per node (wave = 4 nodes): lane-parallel gathers + xor-shuffle reduce.

__global__ __launch_bounds__(256) void k_agg2(const float2* __restrict__ h2s,
                                              const int* __restrict__ rowptr,
                                              const int* __restrict__ csr,
                                              const float* __restrict__ dinv,
                                              const float* __restrict__ b2,
                                              float2* __restrict__ out) {
    int wid = threadIdx.x >> 6, lane = threadIdx.x & 63;
    int sub = lane >> 4, el = lane & 15;
    int node = blockIdx.x * 16 + wid * 4 + sub;   // grid 6250 * 16 = 100000 exactly
    int p0 = rowptr[node], p1 = rowptr[node + 1];
    float ax = 0.f, ay = 0.f;
    for (int p = p0 + el; p < p1; p += 16) {
        float2 g = h2s[csr[p]];
        ax += g.x;
        ay += g.y;
    }
    #pragma unroll
    for (int off = 8; off; off >>= 1) {
        ax += __shfl_xor(ax, off);
        ay += __shfl_xor(ay, off);
    }
    if (el == 0) {
        float2 self = h2s[node];
        float di = dinv[node];
        out[node] = make_float2(fmaf(di, self.x + ax, b2[0]),
                                fmaf(di, self.y + ay, b2[1]));
    }
}

// ---------------- launch ----------------

extern "C" void kernel_launch(void* const* d_in, const int* in_sizes, int n_in,
                              void* d_out, int out_size, void* d_ws, size_t ws_size,
                              hipStream_t stream) {
    const float* x  = (const float*)d_in[0];
    const int*   ei = (const int*)d_in[1];
    const float* W1 = (const float*)d_in[2];
    const float* b1 = (const float*)d_in[3];
    const float* W2 = (const float*)d_in[4];
    const float* b2 = (const float*)d_in[5];
    float* out = (float*)d_out;

    const int* src = ei;
    const int* dst = ei + N_EDGES;

    char* ws = (char*)d_ws;
    size_t off = 0;
    auto alloc = [&](size_t bytes) -> void* {
        void* p = ws + off;
        off += (bytes + 255) & ~(size_t)255;
        return p;
    };
    _Float16* h1s    = (_Float16*)alloc((size_t)N_NODES * HIDDEN * 2);  // 25.6 MB
    float*    dinv   = (float*)   alloc((size_t)N_NODES * 4);
    int*      rowptr = (int*)     alloc((size_t)(N_NODES + 1) * 4);
    int*      bcnt   = (int*)     alloc((size_t)NBKT * 4);
    int*      bktptr = (int*)     alloc((size_t)(NBKT + 1) * 4);
    unsigned* arena  = (unsigned*)alloc((size_t)NBKT * PADCAP * 4);     // 8.0 MB
    int*      csr    = (int*)     alloc((size_t)N_EDGES * 4);           // 6.4 MB
    _Float16* w1t    = (_Float16*)alloc((size_t)HIDDEN * KPAD * 2);     // 45 KB
    float2*   h2s    = (float2*)  alloc((size_t)N_NODES * 8);

    (void)hipMemsetAsync(bcnt, 0, (size_t)NBKT * 4, stream);
    k_w1t<<<(HIDDEN * KPAD + 255) / 256, 256, 0, stream>>>(W1, w1t);
    k_part2<<<NCHUNK, 512, 0, stream>>>(src, dst, bcnt, arena);
    k_btot<<<1, 256, 0, stream>>>(bcnt, bktptr);
    k_sort3<<<NBKT, 1024, 0, stream>>>(arena, bcnt, bktptr, csr, rowptr, dinv);
    k_gemm1<<<(N_NODES / 16 + 3) / 4, 256, 0, stream>>>(x, w1t, dinv, h1s);
    k_agg1<<<N_NODES / 4, 256, 0, stream>>>((const __half2*)h1s, rowptr, csr, dinv, b1, W2, h2s);
    k_agg2<<<N_NODES / 16, 256, 0, stream>>>(h2s, rowptr, csr, dinv, b2, (float2*)out);
}